// Round 10
// baseline (302.661 us; speedup 1.0000x reference)
//
#include <hip/hip_runtime.h>
#include <stdint.h>

typedef __attribute__((ext_vector_type(4))) float floatx4;
typedef __attribute__((ext_vector_type(8))) short shortx8;

#define LN_EPS 1e-5f

__device__ __forceinline__ unsigned short f2b(float f) {
  unsigned u = __builtin_bit_cast(unsigned, f);
  u = (u + 0x7FFFu + ((u >> 16) & 1u)) >> 16;
  return (unsigned short)u;
}
__device__ __forceinline__ float b2f(unsigned short h) {
  return __builtin_bit_cast(float, (unsigned)h << 16);
}

// async global->LDS 16B: lds dest is wave-uniform base; lane i lands at base + i*16
__device__ __forceinline__ void g2l16(const unsigned short* g, unsigned short* l) {
  __builtin_amdgcn_global_load_lds(
      (const __attribute__((address_space(1))) unsigned int*)g,
      (__attribute__((address_space(3))) unsigned int*)l, 16, 0, 0);
}

// ---------------- block reduction helpers (256 threads = 4 waves) -----------
__device__ __forceinline__ float wave_sum(float v) {
#pragma unroll
  for (int o = 32; o; o >>= 1) v += __shfl_down(v, o, 64);
  return v;
}
__device__ __forceinline__ float block_sum(float v, float* s) {
  v = wave_sum(v);
  __syncthreads();
  if ((threadIdx.x & 63) == 0) s[threadIdx.x >> 6] = v;
  __syncthreads();
  return s[0] + s[1] + s[2] + s[3];
}

// ---------------- shared 64x64 bf16 GEMM body (dbuf, g2l16, XCD-swizzled) ---
// Sub-grid: g in [0,total), total % 8 == 0; m0 = (swz%mtiles)*64, n0 = (swz/mtiles)*64.
__device__ __forceinline__ void gemm64_body(
    unsigned short (*As)[64 * 64], unsigned short (*Bs)[64 * 64],
    const unsigned short* __restrict__ A, int lda,
    const unsigned short* __restrict__ Bt, int ldb,
    int K, int mtiles, int total, int g,
    float* __restrict__ out, int ldc) {
  const int tid = threadIdx.x;
  const int wave = tid >> 6, lane = tid & 63;
  const int q = total >> 3;
  const int swz = (g & 7) * q + (g >> 3);
  const int m0 = (swz % mtiles) * 64;
  const int n0 = (swz / mtiles) * 64;
  const int wm = wave & 1, wn = wave >> 1;
  const int l16 = lane & 15, quad = lane >> 4;
  const int srow8 = lane >> 3;
  const int c8 = ((lane & 7) ^ srow8) * 8;

  const unsigned short* gA[2];
  const unsigned short* gB[2];
  int lOff[2];
#pragma unroll
  for (int j = 0; j < 2; j++) {
    const int rb = wave * 16 + j * 8;
    gA[j] = A + (long)(m0 + rb + srow8) * lda + c8;
    gB[j] = Bt + (long)(n0 + rb + srow8) * ldb + c8;
    lOff[j] = rb * 64;
  }
  int offA[2][2], offB[2][2];
#pragma unroll
  for (int ks = 0; ks < 2; ks++)
#pragma unroll
    for (int i = 0; i < 2; i++) {
      int r = wm * 32 + i * 16 + l16;
      offA[ks][i] = r * 64 + (((ks * 4 + quad) ^ (r & 7)) * 8);
      r = wn * 32 + i * 16 + l16;
      offB[ks][i] = r * 64 + (((ks * 4 + quad) ^ (r & 7)) * 8);
    }

  floatx4 acc[2][2] = {};

#pragma unroll
  for (int j = 0; j < 2; j++) {
    g2l16(gA[j], &As[0][lOff[j]]);
    g2l16(gB[j], &Bs[0][lOff[j]]);
  }
  __syncthreads();

  const int nt = K >> 6;
  for (int t = 0; t < nt; t++) {
    const int cur = t & 1;
    if (t + 1 < nt) {
      const int kn = (t + 1) << 6;
#pragma unroll
      for (int j = 0; j < 2; j++) {
        g2l16(gA[j] + kn, &As[cur ^ 1][lOff[j]]);
        g2l16(gB[j] + kn, &Bs[cur ^ 1][lOff[j]]);
      }
    }
#pragma unroll
    for (int ks = 0; ks < 2; ks++) {
      shortx8 af[2], bf[2];
#pragma unroll
      for (int i = 0; i < 2; i++) af[i] = *(const shortx8*)&As[cur][offA[ks][i]];
#pragma unroll
      for (int j = 0; j < 2; j++) bf[j] = *(const shortx8*)&Bs[cur][offB[ks][j]];
#pragma unroll
      for (int i = 0; i < 2; i++)
#pragma unroll
        for (int j = 0; j < 2; j++)
          acc[i][j] = __builtin_amdgcn_mfma_f32_16x16x32_bf16(af[i], bf[j], acc[i][j], 0, 0, 0);
    }
    __syncthreads();
  }

#pragma unroll
  for (int i = 0; i < 2; i++)
#pragma unroll
    for (int j = 0; j < 2; j++) {
      const int rbase = m0 + wm * 32 + i * 16 + quad * 4;
      const int c = n0 + wn * 32 + j * 16 + l16;
#pragma unroll
      for (int r = 0; r < 4; r++)
        out[(long)(rbase + r) * ldc + c] = acc[i][j][r];
    }
}

// ---------------- L1: pw GEMM + 4 transposes + prev-LN + rowsum zero --------
// blocks [0,192): pw = prev(f32) @ Wp(f32)^T -> pwb bf16 (reg-cvt staged)
// blocks [192,7104): 32x32 transpose tiles; block 192 zeroes rowsum
// blocks [7104,8128): prev-LN -> conc[:, 0:1024] (= ps_n, bf16)
__global__ __launch_bounds__(256) void k_prep_pw(
    const float* __restrict__ prev, const float* __restrict__ wp,
    const float* __restrict__ Wu, const float* __restrict__ Wr,
    const float* __restrict__ Wn,
    unsigned short* __restrict__ Wtur, unsigned short* __restrict__ Wtn,
    unsigned short* __restrict__ Wtp, unsigned short* __restrict__ pwb,
    float* __restrict__ rs,
    const float* __restrict__ g_st, const float* __restrict__ be_st,
    unsigned short* __restrict__ conc) {
  __shared__ unsigned short As[2][64 * 64];
  __shared__ unsigned short Bs[2][64 * 64];
  const int bid = blockIdx.x;
  const int tid = threadIdx.x;
  if (bid < 192) {
    const int wave = tid >> 6, lane = tid & 63;
    const int swz = (bid & 7) * 24 + (bid >> 3);  // XCD-bijective over 192
    const int m0 = (swz % 16) * 64;
    const int n0 = (swz / 16) * 64;
    const int wm = wave & 1, wn = wave >> 1;
    const int l16 = lane & 15, quad = lane >> 4;
    const int srow8 = lane >> 3;
    const int c8 = ((lane & 7) ^ srow8) * 8;

    const float* gAf[2];
    const float* gBf[2];
    int lOff[2];
#pragma unroll
    for (int j = 0; j < 2; j++) {
      const int rb = wave * 16 + j * 8;
      gAf[j] = prev + (long)(m0 + rb + srow8) * 1024 + c8;
      gBf[j] = wp + (long)(n0 + rb + srow8) * 1024 + c8;
      lOff[j] = rb * 64;
    }
    int offA[2][2], offB[2][2];
#pragma unroll
    for (int ks = 0; ks < 2; ks++)
#pragma unroll
      for (int i = 0; i < 2; i++) {
        int r = wm * 32 + i * 16 + l16;
        offA[ks][i] = r * 64 + (((ks * 4 + quad) ^ (r & 7)) * 8);
        r = wn * 32 + i * 16 + l16;
        offB[ks][i] = r * 64 + (((ks * 4 + quad) ^ (r & 7)) * 8);
      }

    floatx4 acc[2][2] = {};

#pragma unroll
    for (int j = 0; j < 2; j++) {
      floatx4 a0 = *(const floatx4*)(gAf[j]);
      floatx4 a1 = *(const floatx4*)(gAf[j] + 4);
      floatx4 b0 = *(const floatx4*)(gBf[j]);
      floatx4 b1 = *(const floatx4*)(gBf[j] + 4);
      unsigned short ta[8], tb[8];
#pragma unroll
      for (int i = 0; i < 4; i++) {
        ta[i] = f2b(a0[i]); ta[4 + i] = f2b(a1[i]);
        tb[i] = f2b(b0[i]); tb[4 + i] = f2b(b1[i]);
      }
      *(uint4*)&As[0][lOff[j] + lane * 8] = *(uint4*)ta;
      *(uint4*)&Bs[0][lOff[j] + lane * 8] = *(uint4*)tb;
    }
    __syncthreads();

    const int nt = 16;
    for (int t = 0; t < nt; t++) {
      const int cur = t & 1;
      floatx4 a0[2], a1[2], b0[2], b1[2];
      if (t + 1 < nt) {
        const int kn = (t + 1) << 6;
#pragma unroll
        for (int j = 0; j < 2; j++) {
          a0[j] = *(const floatx4*)(gAf[j] + kn);
          a1[j] = *(const floatx4*)(gAf[j] + kn + 4);
          b0[j] = *(const floatx4*)(gBf[j] + kn);
          b1[j] = *(const floatx4*)(gBf[j] + kn + 4);
        }
      }
#pragma unroll
      for (int ks = 0; ks < 2; ks++) {
        shortx8 af[2], bf[2];
#pragma unroll
        for (int i = 0; i < 2; i++) af[i] = *(const shortx8*)&As[cur][offA[ks][i]];
#pragma unroll
        for (int j = 0; j < 2; j++) bf[j] = *(const shortx8*)&Bs[cur][offB[ks][j]];
#pragma unroll
        for (int i = 0; i < 2; i++)
#pragma unroll
          for (int j = 0; j < 2; j++)
            acc[i][j] = __builtin_amdgcn_mfma_f32_16x16x32_bf16(af[i], bf[j], acc[i][j], 0, 0, 0);
      }
      if (t + 1 < nt) {
#pragma unroll
        for (int j = 0; j < 2; j++) {
          unsigned short ta[8], tb[8];
#pragma unroll
          for (int i = 0; i < 4; i++) {
            ta[i] = f2b(a0[j][i]); ta[4 + i] = f2b(a1[j][i]);
            tb[i] = f2b(b0[j][i]); tb[4 + i] = f2b(b1[j][i]);
          }
          *(uint4*)&As[cur ^ 1][lOff[j] + lane * 8] = *(uint4*)ta;
          *(uint4*)&Bs[cur ^ 1][lOff[j] + lane * 8] = *(uint4*)tb;
        }
      }
      __syncthreads();
    }

#pragma unroll
    for (int i = 0; i < 2; i++)
#pragma unroll
      for (int j = 0; j < 2; j++) {
        const int rbase = m0 + wm * 32 + i * 16 + quad * 4;
        const int c = n0 + wn * 32 + j * 16 + l16;
#pragma unroll
        for (int r = 0; r < 4; r++)
          pwb[(long)(rbase + r) * 768 + c] = f2b(acc[i][j][r]);
      }
    return;
  }
  if (bid >= 7104) {
    // ---- prev-LN -> conc first half (ps_n)
    float* scr = (float*)&As[0][0];
    const long r = bid - 7104;
    floatx4 v = *(const floatx4*)(prev + r * 1024 + tid * 4);
    float s1 = v[0] + v[1] + v[2] + v[3];
    float s2 = v[0] * v[0] + v[1] * v[1] + v[2] * v[2] + v[3] * v[3];
    s1 = block_sum(s1, scr);
    s2 = block_sum(s2, scr);
    const float mean = s1 * (1.0f / 1024.0f);
    const float var = s2 * (1.0f / 1024.0f) - mean * mean;
    const float rstd = rsqrtf(var + LN_EPS);
    unsigned short t4[4];
#pragma unroll
    for (int i = 0; i < 4; i++) {
      const int d = tid * 4 + i;
      t4[i] = f2b((v[i] - mean) * rstd * g_st[d] + be_st[d]);
    }
    *(uint2*)(conc + r * 2048 + tid * 4) = *(uint2*)t4;
    return;
  }
  // ---- transpose part (aliases LDS)
  float(*tile)[33] = (float(*)[33]) & As[0][0];
  if (bid == 192) {
    floatx4 z = {0.f, 0.f, 0.f, 0.f};
    *(floatx4*)(rs + tid * 4) = z;
  }
  int t = bid - 192;
  const float* in;
  unsigned short* out;
  int K, kx, ny;
  if (t < 6144) {
    const int which = t >> 11;
    const int t2 = t & 2047;
    kx = t2 & 63;
    ny = t2 >> 6;
    K = 2048;
    in = which == 0 ? Wu : (which == 1 ? Wr : Wn);
    out = which == 0 ? Wtur : (which == 1 ? Wtur + 1024 * 2048 : Wtn);
  } else {
    const int t2 = t - 6144;
    kx = t2 % 24;
    ny = t2 / 24;
    K = 768;
    in = wp;
    out = Wtp;
  }
  const int N = 1024;
  const int k0 = kx * 32, n0 = ny * 32;
  const int tx = tid & 31, ty = tid >> 5;
#pragma unroll
  for (int i = 0; i < 32; i += 8)
    tile[ty + i][tx] = in[(long)(k0 + ty + i) * N + n0 + tx];
  __syncthreads();
#pragma unroll
  for (int i = 0; i < 32; i += 8)
    out[(long)(n0 + ty + i) * K + k0 + tx] = f2b(tile[tx][ty + i]);
}

// ---------------- L2: scores (blocks 0..511) + gates-kc0 (512..1023) --------
// scores: attnb = exp(pw @ tokens^T * scale) + rowsum atomics
// gates0: gparts[0] = ps_n @ Wtur_top  (A = conc cols 0..1023, K=1024)
__global__ __launch_bounds__(256) void k_scores_g0(
    const unsigned short* __restrict__ pwb,
    const float* __restrict__ toksf,
    unsigned short* __restrict__ attnb, float* __restrict__ rs,
    const unsigned short* __restrict__ conc,
    const unsigned short* __restrict__ Wtur,
    float* __restrict__ gparts) {
  __shared__ unsigned short As[2][64 * 64];
  __shared__ unsigned short Bs[2][64 * 64];
  const int tid = threadIdx.x;
  if (blockIdx.x >= 512) {
    gemm64_body(As, Bs, conc, 2048, Wtur, 2048, 1024, 16, 512,
                blockIdx.x - 512, gparts, 2048);
    return;
  }
  const int wave = tid >> 6, lane = tid & 63;
  const int b = blockIdx.x >> 5;
  const int n0 = (blockIdx.x & 31) * 64;
  const int wm = wave & 1, wn = wave >> 1;
  const int l16 = lane & 15, quad = lane >> 4;
  const int srow8 = lane >> 3;
  const int c8 = ((lane & 7) ^ srow8) * 8;
  const unsigned short* Ab = pwb + (long)b * 49152;

  const unsigned short* gA[2];
  const float* gBf[2];
  int lOff[2];
#pragma unroll
  for (int j = 0; j < 2; j++) {
    const int rb = wave * 16 + j * 8;
    gA[j] = Ab + (long)(rb + srow8) * 768 + c8;
    gBf[j] = toksf + (long)b * 1572864 + (long)(n0 + rb + srow8) * 768 + c8;
    lOff[j] = rb * 64;
  }
  int offA[2][2], offB[2][2];
#pragma unroll
  for (int ks = 0; ks < 2; ks++)
#pragma unroll
    for (int i = 0; i < 2; i++) {
      int r = wm * 32 + i * 16 + l16;
      offA[ks][i] = r * 64 + (((ks * 4 + quad) ^ (r & 7)) * 8);
      r = wn * 32 + i * 16 + l16;
      offB[ks][i] = r * 64 + (((ks * 4 + quad) ^ (r & 7)) * 8);
    }

  floatx4 acc[2][2] = {};

#pragma unroll
  for (int j = 0; j < 2; j++) {
    g2l16(gA[j], &As[0][lOff[j]]);
    floatx4 v0 = *(const floatx4*)(gBf[j]);
    floatx4 v1 = *(const floatx4*)(gBf[j] + 4);
    unsigned short t8[8];
#pragma unroll
    for (int i = 0; i < 4; i++) { t8[i] = f2b(v0[i]); t8[4 + i] = f2b(v1[i]); }
    *(uint4*)&Bs[0][lOff[j] + lane * 8] = *(uint4*)t8;
  }
  __syncthreads();

  const int nt = 12;  // K = 768
  for (int t = 0; t < nt; t++) {
    const int cur = t & 1;
    floatx4 w0[2], w1[2];
    if (t + 1 < nt) {
      const int kn = (t + 1) << 6;
#pragma unroll
      for (int j = 0; j < 2; j++) {
        g2l16(gA[j] + kn, &As[cur ^ 1][lOff[j]]);
        w0[j] = *(const floatx4*)(gBf[j] + kn);
        w1[j] = *(const floatx4*)(gBf[j] + kn + 4);
      }
    }
#pragma unroll
    for (int ks = 0; ks < 2; ks++) {
      shortx8 af[2], bf[2];
#pragma unroll
      for (int i = 0; i < 2; i++) af[i] = *(const shortx8*)&As[cur][offA[ks][i]];
#pragma unroll
      for (int j = 0; j < 2; j++) bf[j] = *(const shortx8*)&Bs[cur][offB[ks][j]];
#pragma unroll
      for (int i = 0; i < 2; i++)
#pragma unroll
        for (int j = 0; j < 2; j++)
          acc[i][j] = __builtin_amdgcn_mfma_f32_16x16x32_bf16(af[i], bf[j], acc[i][j], 0, 0, 0);
    }
    if (t + 1 < nt) {
#pragma unroll
      for (int j = 0; j < 2; j++) {
        unsigned short t8[8];
#pragma unroll
        for (int i = 0; i < 4; i++) { t8[i] = f2b(w0[j][i]); t8[4 + i] = f2b(w1[j][i]); }
        *(uint4*)&Bs[cur ^ 1][lOff[j] + lane * 8] = *(uint4*)t8;
      }
    }
    __syncthreads();
  }

#pragma unroll
  for (int i = 0; i < 2; i++) {
    float psum[4] = {0.f, 0.f, 0.f, 0.f};
#pragma unroll
    for (int j = 0; j < 2; j++) {
      const int rbase = wm * 32 + i * 16 + quad * 4;
      const int c = n0 + wn * 32 + j * 16 + l16;
#pragma unroll
      for (int r = 0; r < 4; r++) {
        const float e = expf(acc[i][j][r] * 0.03125f);
        attnb[(long)b * 131072 + (long)(rbase + r) * 2048 + c] = f2b(e);
        psum[r] += e;
      }
    }
#pragma unroll
    for (int r = 0; r < 4; r++) {
      float s = psum[r];
      s += __shfl_xor(s, 1, 64);
      s += __shfl_xor(s, 2, 64);
      s += __shfl_xor(s, 4, 64);
      s += __shfl_xor(s, 8, 64);
      if (l16 == 0)
        atomicAdd(rs + (long)b * 64 + wm * 32 + i * 16 + quad * 4 + r, s);
    }
  }
}

// ---------------- rw = attnb(exp) @ tokens(f32) via MFMA, K-split x2 --------
__global__ __launch_bounds__(256) void k_routed_mfma(
    const unsigned short* __restrict__ attnb,
    const float* __restrict__ tokf,
    float* __restrict__ parts) {
  __shared__ unsigned short As[64 * 40];
  __shared__ unsigned short Bs[32 * 66];
  const int kc = blockIdx.x, nt = blockIdx.y, b = blockIdx.z;
  const int tid = threadIdx.x;
  const int wave = tid >> 6, lane = tid & 63;
  const int wm = wave & 1, wn = wave >> 1;
  const int l16 = lane & 15, quad = lane >> 4;
  const int n0 = nt * 64;
  const long abase = (long)b * 131072 + (long)kc * 1024;
  const long tbase = ((long)b * 2048 + (long)kc * 1024) * 768;
  const int srow = tid >> 2, skc = (tid & 3) * 8;
  const int bk = tid >> 3, bd = (tid & 7) * 8;

  floatx4 acc[2][2] = {};

  uint4 pa = *(const uint4*)(attnb + abase + (long)srow * 2048 + skc);
  floatx4 f0 = *(const floatx4*)(tokf + tbase + (long)bk * 768 + n0 + bd);
  floatx4 f1 = *(const floatx4*)(tokf + tbase + (long)bk * 768 + n0 + bd + 4);

  for (int k0 = 0; k0 < 1024; k0 += 32) {
    *(uint4*)&As[srow * 40 + skc] = pa;
    {
      unsigned short t8[8];
#pragma unroll
      for (int i = 0; i < 4; i++) { t8[i] = f2b(f0[i]); t8[4 + i] = f2b(f1[i]); }
      unsigned short* dst = &Bs[bk * 66 + bd];
#pragma unroll
      for (int w2 = 0; w2 < 4; w2++) *(unsigned*)(dst + w2 * 2) = ((unsigned*)t8)[w2];
    }
    if (k0 + 32 < 1024) {
      pa = *(const uint4*)(attnb + abase + (long)srow * 2048 + (k0 + 32) + skc);
      f0 = *(const floatx4*)(tokf + tbase + (long)(k0 + 32 + bk) * 768 + n0 + bd);
      f1 = *(const floatx4*)(tokf + tbase + (long)(k0 + 32 + bk) * 768 + n0 + bd + 4);
    }
    asm volatile("s_waitcnt lgkmcnt(0)" ::: "memory");
    __builtin_amdgcn_s_barrier();
    __builtin_amdgcn_sched_barrier(0);

    shortx8 a0 = *(const shortx8*)&As[(wm * 32 + 0  + l16) * 40 + quad * 8];
    shortx8 a1 = *(const shortx8*)&As[(wm * 32 + 16 + l16) * 40 + quad * 8];
    shortx8 b0, b1;
#pragma unroll
    for (int j = 0; j < 8; j++) {
      b0[j] = *(const short*)&Bs[(quad * 8 + j) * 66 + wn * 32 + l16];
      b1[j] = *(const short*)&Bs[(quad * 8 + j) * 66 + wn * 32 + 16 + l16];
    }
    acc[0][0] = __builtin_amdgcn_mfma_f32_16x16x32_bf16(a0, b0, acc[0][0], 0, 0, 0);
    acc[0][1] = __builtin_amdgcn_mfma_f32_16x16x32_bf16(a0, b1, acc[0][1], 0, 0, 0);
    acc[1][0] = __builtin_amdgcn_mfma_f32_16x16x32_bf16(a1, b0, acc[1][0], 0, 0, 0);
    acc[1][1] = __builtin_amdgcn_mfma_f32_16x16x32_bf16(a1, b1, acc[1][1], 0, 0, 0);
    __builtin_amdgcn_s_barrier();
  }

#pragma unroll
  for (int im = 0; im < 2; im++)
#pragma unroll
    for (int in_ = 0; in_ < 2; in_++) {
      const int rbase = wm * 32 + im * 16 + quad * 4;
      const int c = n0 + wn * 32 + in_ * 16 + l16;
#pragma unroll
      for (int r = 0; r < 4; r++)
        parts[(long)kc * 786432 + ((long)b * 64 + rbase + r) * 768 + c] =
            acc[im][in_][r];
    }
}

// ---------------- proj2: A = sum of 2 f32 parts (reg-cvt), B = Wtp ---------
__global__ __launch_bounds__(256) void k_proj2(
    const float* __restrict__ P0, int lda,
    const unsigned short* __restrict__ Bt, int ldb,
    int K,
    const float* __restrict__ bp, const float* __restrict__ rowsum,
    float* __restrict__ out, int ldc) {
  __shared__ unsigned short As[2][64 * 64];
  __shared__ unsigned short Bs[2][64 * 64];
  const int tid = threadIdx.x;
  const int wave = tid >> 6, lane = tid & 63;
  const int flat = blockIdx.x;
  const int swz = (flat & 7) * 32 + (flat >> 3);  // bijective over 256
  const int m0 = (swz % 16) * 64;
  const int n0 = (swz / 16) * 64;
  const int wm = wave & 1, wn = wave >> 1;
  const int l16 = lane & 15, quad = lane >> 4;
  const int srow8 = lane >> 3;
  const int c8 = ((lane & 7) ^ srow8) * 8;

  const float* gAf[2];
  const unsigned short* gB[2];
  int lOff[2];
#pragma unroll
  for (int j = 0; j < 2; j++) {
    const int rb = wave * 16 + j * 8;
    gAf[j] = P0 + (long)(m0 + rb + srow8) * lda + c8;
    gB[j] = Bt + (long)(n0 + rb + srow8) * ldb + c8;
    lOff[j] = rb * 64;
  }
  int offA[2][2], offB[2][2];
#pragma unroll
  for (int ks = 0; ks < 2; ks++)
#pragma unroll
    for (int i = 0; i < 2; i++) {
      int r = wm * 32 + i * 16 + l16;
      offA[ks][i] = r * 64 + (((ks * 4 + quad) ^ (r & 7)) * 8);
      r = wn * 32 + i * 16 + l16;
      offB[ks][i] = r * 64 + (((ks * 4 + quad) ^ (r & 7)) * 8);
    }

  floatx4 acc[2][2] = {};

#pragma unroll
  for (int j = 0; j < 2; j++) {
    g2l16(gB[j], &Bs[0][lOff[j]]);
    floatx4 a0 = *(const floatx4*)(gAf[j]);
    floatx4 a1 = *(const floatx4*)(gAf[j] + 4);
    floatx4 b0 = *(const floatx4*)(gAf[j] + 786432);
    floatx4 b1 = *(const floatx4*)(gAf[j] + 786432 + 4);
    unsigned short t8[8];
#pragma unroll
    for (int i = 0; i < 4; i++) { t8[i] = f2b(a0[i] + b0[i]); t8[4 + i] = f2b(a1[i] + b1[i]); }
    *(uint4*)&As[0][lOff[j] + lane * 8] = *(uint4*)t8;
  }
  __syncthreads();

  const int nt = K >> 6;
  for (int t = 0; t < nt; t++) {
    const int cur = t & 1;
    floatx4 a0[2], a1[2], p0[2], p1[2];
    if (t + 1 < nt) {
      const int kn = (t + 1) << 6;
#pragma unroll
      for (int j = 0; j < 2; j++) {
        g2l16(gB[j] + kn, &Bs[cur ^ 1][lOff[j]]);
        a0[j] = *(const floatx4*)(gAf[j] + kn);
        a1[j] = *(const floatx4*)(gAf[j] + kn + 4);
        p0[j] = *(const floatx4*)(gAf[j] + kn + 786432);
        p1[j] = *(const floatx4*)(gAf[j] + kn + 786432 + 4);
      }
    }
#pragma unroll
    for (int ks = 0; ks < 2; ks++) {
      shortx8 af[2], bf[2];
#pragma unroll
      for (int i = 0; i < 2; i++) af[i] = *(const shortx8*)&As[cur][offA[ks][i]];
#pragma unroll
      for (int j = 0; j < 2; j++) bf[j] = *(const shortx8*)&Bs[cur][offB[ks][j]];
#pragma unroll
      for (int i = 0; i < 2; i++)
#pragma unroll
        for (int j = 0; j < 2; j++)
          acc[i][j] = __builtin_amdgcn_mfma_f32_16x16x32_bf16(af[i], bf[j], acc[i][j], 0, 0, 0);
    }
    if (t + 1 < nt) {
#pragma unroll
      for (int j = 0; j < 2; j++) {
        unsigned short t8[8];
#pragma unroll
        for (int i = 0; i < 4; i++) {
          t8[i] = f2b(a0[j][i] + p0[j][i]);
          t8[4 + i] = f2b(a1[j][i] + p1[j][i]);
        }
        *(uint4*)&As[cur ^ 1][lOff[j] + lane * 8] = *(uint4*)t8;
      }
    }
    __syncthreads();
  }

#pragma unroll
  for (int i = 0; i < 2; i++)
#pragma unroll
    for (int j = 0; j < 2; j++) {
      const int rbase = m0 + wm * 32 + i * 16 + quad * 4;
      const int c = n0 + wn * 32 + j * 16 + l16;
#pragma unroll
      for (int r = 0; r < 4; r++) {
        const int row = rbase + r;
        out[(long)row * ldc + c] = acc[i][j][r] + rowsum[row] * bp[c];
      }
    }
}

// ---------------- routed LayerNorm -> conc second half + candA second half --
__global__ __launch_bounds__(256) void k_ln_routed(
    const float* __restrict__ routed,
    const float* __restrict__ g_in, const float* __restrict__ be_in,
    unsigned short* __restrict__ conc, unsigned short* __restrict__ candA) {
  __shared__ float scr[4];
  const long r = blockIdx.x;
  const int t = threadIdx.x;
  floatx4 v = *(const floatx4*)(routed + r * 1024 + t * 4);
  float s1 = v[0] + v[1] + v[2] + v[3];
  float s2 = v[0] * v[0] + v[1] * v[1] + v[2] * v[2] + v[3] * v[3];
  s1 = block_sum(s1, scr);
  s2 = block_sum(s2, scr);
  const float mean = s1 * (1.0f / 1024.0f);
  const float var = s2 * (1.0f / 1024.0f) - mean * mean;
  const float rstd = rsqrtf(var + LN_EPS);
  unsigned short t4[4];
#pragma unroll
  for (int i = 0; i < 4; i++) {
    const int d = t * 4 + i;
    t4[i] = f2b((v[i] - mean) * rstd * g_in[d] + be_in[d]);
  }
  *(uint2*)(conc + r * 2048 + 1024 + t * 4) = *(uint2*)t4;
  *(uint2*)(candA + r * 2048 + 1024 + t * 4) = *(uint2*)t4;
}

// ---------------- L6: gates-kc1 (blocks 0..511) + cand-kc1 (512..767) -------
// gates1: gparts[1] = in_n @ Wtur_bot   (A = conc cols 1024.., K=1024)
// cand2:  cparts[1] = in_n @ Wtn_bot    (A = candA cols 1024.., K=1024)
__global__ __launch_bounds__(256) void k_g1_c2(
    const unsigned short* __restrict__ conc,
    const unsigned short* __restrict__ Wtur, float* __restrict__ gparts,
    const unsigned short* __restrict__ candA,
    const unsigned short* __restrict__ Wtn, float* __restrict__ cparts) {
  __shared__ unsigned short As[2][64 * 64];
  __shared__ unsigned short Bs[2][64 * 64];
  if (blockIdx.x < 512) {
    gemm64_body(As, Bs, conc + 1024, 2048, Wtur + 1024, 2048, 1024, 16, 512,
                blockIdx.x, gparts + 2097152, 2048);
  } else {
    gemm64_body(As, Bs, candA + 1024, 2048, Wtn + 1024, 2048, 1024, 16, 256,
                blockIdx.x - 512, cparts + 1048576, 1024);
  }
}

// ---------------- gates epilogue: sigmoid(p0+p1+bias) -> ubuf / r*psn -------
__global__ __launch_bounds__(256) void k_gate_epi(
    const float* __restrict__ gparts,  // [2][1024][2048]
    const float* __restrict__ bu, const float* __restrict__ br,
    const unsigned short* __restrict__ conc,
    float* __restrict__ ubuf, unsigned short* __restrict__ candA) {
  const int row = blockIdx.x >> 1;
  const int half = blockIdx.x & 1;
  const int t = threadIdx.x;
  const long base = (long)row * 2048 + half * 1024 + t * 4;
  floatx4 p0 = *(const floatx4*)(gparts + base);
  floatx4 p1 = *(const floatx4*)(gparts + 2097152 + base);
  const float* bias = half ? br : bu;
  floatx4 bv = *(const floatx4*)(bias + t * 4);
  if (!half) {
    floatx4 o;
#pragma unroll
    for (int i = 0; i < 4; i++)
      o[i] = 1.0f / (1.0f + expf(-(p0[i] + p1[i] + bv[i])));
    *(floatx4*)(ubuf + (long)row * 1024 + t * 4) = o;
  } else {
    unsigned short t4[4];
#pragma unroll
    for (int i = 0; i < 4; i++) {
      float rr = 1.0f / (1.0f + expf(-(p0[i] + p1[i] + bv[i])));
      t4[i] = f2b(rr * b2f(conc[(long)row * 2048 + t * 4 + i]));
    }
    *(uint2*)(candA + (long)row * 2048 + t * 4) = *(uint2*)t4;
  }
}

// ---------------- cand-kc0: cparts[0] = (r*psn) @ Wtn_top -------------------
__global__ __launch_bounds__(256) void k_cand1(
    const unsigned short* __restrict__ candA,
    const unsigned short* __restrict__ Wtn, float* __restrict__ cparts) {
  __shared__ unsigned short As[2][64 * 64];
  __shared__ unsigned short Bs[2][64 * 64];
  gemm64_body(As, Bs, candA, 2048, Wtn, 2048, 1024, 16, 256,
              blockIdx.x, cparts, 1024);
}

// ---------------- final: cand-epilogue (2 parts) + LayerNorm -> f32 output --
__global__ __launch_bounds__(256) void k_ln_out(
    const float* __restrict__ cparts,  // [2][1024][1024]
    const float* __restrict__ ubuf, const float* __restrict__ prev,
    const float* __restrict__ bn,
    const float* __restrict__ g, const float* __restrict__ be,
    float* __restrict__ out) {
  __shared__ float scr[4];
  const long r = blockIdx.x;
  const int t = threadIdx.x;
  floatx4 p0 = *(const floatx4*)(cparts + r * 1024 + t * 4);
  floatx4 p1 = *(const floatx4*)(cparts + 1048576 + r * 1024 + t * 4);
  floatx4 uu = *(const floatx4*)(ubuf + r * 1024 + t * 4);
  floatx4 pv = *(const floatx4*)(prev + r * 1024 + t * 4);
  floatx4 bv = *(const floatx4*)(bn + t * 4);
  floatx4 v;
#pragma unroll
  for (int i = 0; i < 4; i++) {
    const float cand = tanhf(p0[i] + p1[i] + bv[i]);
    v[i] = (1.0f - uu[i]) * pv[i] + uu[i] * cand;
  }
  float s1 = v[0] + v[1] + v[2] + v[3];
  float s2 = v[0] * v[0] + v[1] * v[1] + v[2] * v[2] + v[3] * v[3];
  s1 = block_sum(s1, scr);
  s2 = block_sum(s2, scr);
  const float mean = s1 * (1.0f / 1024.0f);
  const float var = s2 * (1.0f / 1024.0f) - mean * mean;
  const float rstd = rsqrtf(var + LN_EPS);
  floatx4 o;
#pragma unroll
  for (int i = 0; i < 4; i++) {
    const int d = t * 4 + i;
    o[i] = (v[i] - mean) * rstd * g[d] + be[d];
  }
  *(floatx4*)(out + r * 1024 + t * 4) = o;
}

// ---------------------------------------------------------------------------
extern "C" void kernel_launch(void* const* d_in, const int* in_sizes, int n_in,
                              void* d_out, int out_size, void* d_ws, size_t ws_size,
                              hipStream_t stream) {
  (void)in_sizes; (void)n_in; (void)out_size; (void)ws_size;
  const float* prev  = (const float*)d_in[0];
  const float* toks  = (const float*)d_in[1];
  const float* Wp    = (const float*)d_in[2];
  const float* bp    = (const float*)d_in[3];
  const float* g_st  = (const float*)d_in[4];
  const float* be_st = (const float*)d_in[5];
  const float* g_in  = (const float*)d_in[6];
  const float* be_in = (const float*)d_in[7];
  const float* g_o   = (const float*)d_in[8];
  const float* be_o  = (const float*)d_in[9];
  const float* Wu    = (const float*)d_in[10];
  const float* bu    = (const float*)d_in[11];
  const float* Wr    = (const float*)d_in[12];
  const float* br    = (const float*)d_in[13];
  const float* Wn    = (const float*)d_in[14];
  const float* bn    = (const float*)d_in[15];
  float* out = (float*)d_out;

  // ---- workspace (~70 MB), identical to round-7 layout
  char* ws = (char*)d_ws;
  unsigned short* Wtp   = (unsigned short*)ws; ws += 1572864;   // 1024x768 bf16
  unsigned short* pwb   = (unsigned short*)ws; ws += 1572864;   // 1024x768 bf16
  unsigned short* attnb = (unsigned short*)ws; ws += 4194304;   // 16x64x2048 bf16
  float*          rowsum= (float*)ws;          ws += 4096;      // 1024 f32
  float*          parts = (float*)ws;          ws += 6291456;   // 2x 1024x768 f32
  float*          routed= (float*)ws;          ws += 4194304;   // 1024x1024 f32
  unsigned short* conc  = (unsigned short*)ws; ws += 4194304;   // 1024x2048 bf16
  unsigned short* candA = (unsigned short*)ws; ws += 4194304;   // 1024x2048 bf16
  float*          ubuf  = (float*)ws;          ws += 4194304;   // 1024x1024 f32
  unsigned short* Wtur  = (unsigned short*)ws; ws += 8388608;   // 2048x2048 bf16
  unsigned short* Wtn   = (unsigned short*)ws; ws += 4194304;   // 1024x2048 bf16
  float*          gparts= (float*)ws;          ws += 16777216;  // 2x 1024x2048 f32
  float*          cparts= (float*)ws;          ws += 8388608;   // 2x 1024x1024 f32

  const dim3 blk(256);

  // 1. prep: pw GEMM + transposes + prev-LN (-> conc first half) + rowsum zero
  k_prep_pw<<<dim3(8128), blk, 0, stream>>>(prev, Wp, Wu, Wr, Wn,
                                            Wtur, Wtn, Wtp, pwb, rowsum,
                                            g_st, be_st, conc);
  // 2. scores + gates-kc0 (ps_n @ Wtur_top) co-launched, 1024 blocks
  k_scores_g0<<<dim3(1024), blk, 0, stream>>>(pwb, toks, attnb, rowsum,
                                              conc, Wtur, gparts);
  // 3. rw partials = w @ tokens(f32), K-split x2, 384 blocks
  k_routed_mfma<<<dim3(2, 12, 16), blk, 0, stream>>>(attnb, toks, parts);
  // 4. routed = (parts0+parts1) @ W_proj + rowsum*b_proj, 256 blocks
  k_proj2<<<dim3(256), blk, 0, stream>>>(parts, 768, Wtp, 768, 768,
                                         bp, rowsum, routed, 1024);
  // 5. routed LN -> conc/candA second halves
  k_ln_routed<<<dim3(1024), blk, 0, stream>>>(routed, g_in, be_in, conc, candA);
  // 6. gates-kc1 + cand-kc1 (both only need in_n), 768 blocks
  k_g1_c2<<<dim3(768), blk, 0, stream>>>(conc, Wtur, gparts, candA, Wtn, cparts);
  // 7. gates epilogue: sigmoid + r*ps_n, 2048 blocks
  k_gate_epi<<<dim3(2048), blk, 0, stream>>>(gparts, bu, br, conc, ubuf, candA);
  // 8. cand-kc0 ((r*psn) @ Wtn_top), 256 blocks
  k_cand1<<<dim3(256), blk, 0, stream>>>(candA, Wtn, cparts);
  // 9. fused cand-epilogue + final LN -> output
  k_ln_out<<<dim3(1024), blk, 0, stream>>>(cparts, ubuf, prev, bn, g_o, be_o, out);
}

// Round 11
// 300.726 us; speedup vs baseline: 1.0064x; 1.0064x over previous
//
#include <hip/hip_runtime.h>
#include <stdint.h>

typedef __attribute__((ext_vector_type(4))) float floatx4;
typedef __attribute__((ext_vector_type(8))) short shortx8;

#define LN_EPS 1e-5f

__device__ __forceinline__ unsigned short f2b(float f) {
  unsigned u = __builtin_bit_cast(unsigned, f);
  u = (u + 0x7FFFu + ((u >> 16) & 1u)) >> 16;
  return (unsigned short)u;
}
__device__ __forceinline__ float b2f(unsigned short h) {
  return __builtin_bit_cast(float, (unsigned)h << 16);
}

// async global->LDS 16B: lds dest is wave-uniform base; lane i lands at base + i*16
__device__ __forceinline__ void g2l16(const unsigned short* g, unsigned short* l) {
  __builtin_amdgcn_global_load_lds(
      (const __attribute__((address_space(1))) unsigned int*)g,
      (__attribute__((address_space(3))) unsigned int*)l, 16, 0, 0);
}

// ---------------- block reduction helpers (256 threads = 4 waves) -----------
__device__ __forceinline__ float wave_sum(float v) {
#pragma unroll
  for (int o = 32; o; o >>= 1) v += __shfl_down(v, o, 64);
  return v;
}
__device__ __forceinline__ float block_sum(float v, float* s) {
  v = wave_sum(v);
  __syncthreads();
  if ((threadIdx.x & 63) == 0) s[threadIdx.x >> 6] = v;
  __syncthreads();
  return s[0] + s[1] + s[2] + s[3];
}

// ---------------- merged: pw GEMM (blocks 0..191) + transposes + rowsum -----
__global__ __launch_bounds__(256) void k_prep_pw(
    const float* __restrict__ prev, const float* __restrict__ wp,
    const float* __restrict__ Wu, const float* __restrict__ Wr,
    const float* __restrict__ Wn,
    unsigned short* __restrict__ Wtur, unsigned short* __restrict__ Wtn,
    unsigned short* __restrict__ Wtp, unsigned short* __restrict__ pwb,
    float* __restrict__ rs) {
  __shared__ unsigned short As[2][64 * 64];
  __shared__ unsigned short Bs[2][64 * 64];
  const int bid = blockIdx.x;
  const int tid = threadIdx.x;
  if (bid < 192) {
    const int wave = tid >> 6, lane = tid & 63;
    const int swz = (bid & 7) * 24 + (bid >> 3);  // XCD-bijective over 192
    const int m0 = (swz % 16) * 64;
    const int n0 = (swz / 16) * 64;
    const int wm = wave & 1, wn = wave >> 1;
    const int l16 = lane & 15, quad = lane >> 4;
    const int srow8 = lane >> 3;
    const int c8 = ((lane & 7) ^ srow8) * 8;

    const float* gAf[2];
    const float* gBf[2];
    int lOff[2];
#pragma unroll
    for (int j = 0; j < 2; j++) {
      const int rb = wave * 16 + j * 8;
      gAf[j] = prev + (long)(m0 + rb + srow8) * 1024 + c8;
      gBf[j] = wp + (long)(n0 + rb + srow8) * 1024 + c8;
      lOff[j] = rb * 64;
    }
    int offA[2][2], offB[2][2];
#pragma unroll
    for (int ks = 0; ks < 2; ks++)
#pragma unroll
      for (int i = 0; i < 2; i++) {
        int r = wm * 32 + i * 16 + l16;
        offA[ks][i] = r * 64 + (((ks * 4 + quad) ^ (r & 7)) * 8);
        r = wn * 32 + i * 16 + l16;
        offB[ks][i] = r * 64 + (((ks * 4 + quad) ^ (r & 7)) * 8);
      }

    floatx4 acc[2][2] = {};

#pragma unroll
    for (int j = 0; j < 2; j++) {
      floatx4 a0 = *(const floatx4*)(gAf[j]);
      floatx4 a1 = *(const floatx4*)(gAf[j] + 4);
      floatx4 b0 = *(const floatx4*)(gBf[j]);
      floatx4 b1 = *(const floatx4*)(gBf[j] + 4);
      unsigned short ta[8], tb[8];
#pragma unroll
      for (int i = 0; i < 4; i++) {
        ta[i] = f2b(a0[i]); ta[4 + i] = f2b(a1[i]);
        tb[i] = f2b(b0[i]); tb[4 + i] = f2b(b1[i]);
      }
      *(uint4*)&As[0][lOff[j] + lane * 8] = *(uint4*)ta;
      *(uint4*)&Bs[0][lOff[j] + lane * 8] = *(uint4*)tb;
    }
    __syncthreads();

    const int nt = 16;
    for (int t = 0; t < nt; t++) {
      const int cur = t & 1;
      floatx4 a0[2], a1[2], b0[2], b1[2];
      if (t + 1 < nt) {
        const int kn = (t + 1) << 6;
#pragma unroll
        for (int j = 0; j < 2; j++) {
          a0[j] = *(const floatx4*)(gAf[j] + kn);
          a1[j] = *(const floatx4*)(gAf[j] + kn + 4);
          b0[j] = *(const floatx4*)(gBf[j] + kn);
          b1[j] = *(const floatx4*)(gBf[j] + kn + 4);
        }
      }
#pragma unroll
      for (int ks = 0; ks < 2; ks++) {
        shortx8 af[2], bf[2];
#pragma unroll
        for (int i = 0; i < 2; i++) af[i] = *(const shortx8*)&As[cur][offA[ks][i]];
#pragma unroll
        for (int j = 0; j < 2; j++) bf[j] = *(const shortx8*)&Bs[cur][offB[ks][j]];
#pragma unroll
        for (int i = 0; i < 2; i++)
#pragma unroll
          for (int j = 0; j < 2; j++)
            acc[i][j] = __builtin_amdgcn_mfma_f32_16x16x32_bf16(af[i], bf[j], acc[i][j], 0, 0, 0);
      }
      if (t + 1 < nt) {
#pragma unroll
        for (int j = 0; j < 2; j++) {
          unsigned short ta[8], tb[8];
#pragma unroll
          for (int i = 0; i < 4; i++) {
            ta[i] = f2b(a0[j][i]); ta[4 + i] = f2b(a1[j][i]);
            tb[i] = f2b(b0[j][i]); tb[4 + i] = f2b(b1[j][i]);
          }
          *(uint4*)&As[cur ^ 1][lOff[j] + lane * 8] = *(uint4*)ta;
          *(uint4*)&Bs[cur ^ 1][lOff[j] + lane * 8] = *(uint4*)tb;
        }
      }
      __syncthreads();
    }

#pragma unroll
    for (int i = 0; i < 2; i++)
#pragma unroll
      for (int j = 0; j < 2; j++) {
        const int rbase = m0 + wm * 32 + i * 16 + quad * 4;
        const int c = n0 + wn * 32 + j * 16 + l16;
#pragma unroll
        for (int r = 0; r < 4; r++)
          pwb[(long)(rbase + r) * 768 + c] = f2b(acc[i][j][r]);
      }
    return;
  }
  // ---- transpose part (aliases LDS)
  float(*tile)[33] = (float(*)[33]) & As[0][0];
  if (bid == 192) {
    floatx4 z = {0.f, 0.f, 0.f, 0.f};
    *(floatx4*)(rs + tid * 4) = z;
  }
  int t = bid - 192;
  const float* in;
  unsigned short* out;
  int K, kx, ny;
  if (t < 6144) {
    const int which = t >> 11;
    const int t2 = t & 2047;
    kx = t2 & 63;
    ny = t2 >> 6;
    K = 2048;
    in = which == 0 ? Wu : (which == 1 ? Wr : Wn);
    out = which == 0 ? Wtur : (which == 1 ? Wtur + 1024 * 2048 : Wtn);
  } else {
    const int t2 = t - 6144;
    kx = t2 % 24;
    ny = t2 / 24;
    K = 768;
    in = wp;
    out = Wtp;
  }
  const int N = 1024;
  const int k0 = kx * 32, n0 = ny * 32;
  const int tx = tid & 31, ty = tid >> 5;
#pragma unroll
  for (int i = 0; i < 32; i += 8)
    tile[ty + i][tx] = in[(long)(k0 + ty + i) * N + n0 + tx];
  __syncthreads();
#pragma unroll
  for (int i = 0; i < 32; i += 8)
    out[(long)(n0 + ty + i) * K + k0 + tx] = f2b(tile[tx][ty + i]);
}

// ---------------- gates: 64x64 dbuf GEMM, K=2048 unsplit, mode-5 epilogue ---
// c<1024: ubuf = sigmoid(v+bu[c]); else candA[.][c-1024] = sigmoid(v+br)*ps_n
__global__ __launch_bounds__(256) void k_gates5(
    const unsigned short* __restrict__ conc,   // A [1024][2048] bf16
    const unsigned short* __restrict__ Wtur,   // Bt [2048][2048] bf16
    const float* __restrict__ bu, const float* __restrict__ br,
    float* __restrict__ ubuf, unsigned short* __restrict__ candA) {
  __shared__ unsigned short As[2][64 * 64];
  __shared__ unsigned short Bs[2][64 * 64];
  const int tid = threadIdx.x;
  const int wave = tid >> 6, lane = tid & 63;
  const int flat = blockIdx.x + blockIdx.y * gridDim.x;
  const int q = (gridDim.x * gridDim.y) >> 3;
  const int swz = (flat & 7) * q + (flat >> 3);
  const int m0 = (swz % gridDim.x) * 64;
  const int n0 = (swz / gridDim.x) * 64;
  const int wm = wave & 1, wn = wave >> 1;
  const int l16 = lane & 15, quad = lane >> 4;
  const int srow8 = lane >> 3;
  const int c8 = ((lane & 7) ^ srow8) * 8;

  const unsigned short* gA[2];
  const unsigned short* gB[2];
  int lOff[2];
#pragma unroll
  for (int j = 0; j < 2; j++) {
    const int rb = wave * 16 + j * 8;
    gA[j] = conc + (long)(m0 + rb + srow8) * 2048 + c8;
    gB[j] = Wtur + (long)(n0 + rb + srow8) * 2048 + c8;
    lOff[j] = rb * 64;
  }
  int offA[2][2], offB[2][2];
#pragma unroll
  for (int ks = 0; ks < 2; ks++)
#pragma unroll
    for (int i = 0; i < 2; i++) {
      int r = wm * 32 + i * 16 + l16;
      offA[ks][i] = r * 64 + (((ks * 4 + quad) ^ (r & 7)) * 8);
      r = wn * 32 + i * 16 + l16;
      offB[ks][i] = r * 64 + (((ks * 4 + quad) ^ (r & 7)) * 8);
    }

  floatx4 acc[2][2] = {};

#pragma unroll
  for (int j = 0; j < 2; j++) {
    g2l16(gA[j], &As[0][lOff[j]]);
    g2l16(gB[j], &Bs[0][lOff[j]]);
  }
  __syncthreads();

  const int nt = 32;  // K = 2048
  for (int t = 0; t < nt; t++) {
    const int cur = t & 1;
    if (t + 1 < nt) {
      const int kn = (t + 1) << 6;
#pragma unroll
      for (int j = 0; j < 2; j++) {
        g2l16(gA[j] + kn, &As[cur ^ 1][lOff[j]]);
        g2l16(gB[j] + kn, &Bs[cur ^ 1][lOff[j]]);
      }
    }
#pragma unroll
    for (int ks = 0; ks < 2; ks++) {
      shortx8 af[2], bf[2];
#pragma unroll
      for (int i = 0; i < 2; i++) af[i] = *(const shortx8*)&As[cur][offA[ks][i]];
#pragma unroll
      for (int j = 0; j < 2; j++) bf[j] = *(const shortx8*)&Bs[cur][offB[ks][j]];
#pragma unroll
      for (int i = 0; i < 2; i++)
#pragma unroll
        for (int j = 0; j < 2; j++)
          acc[i][j] = __builtin_amdgcn_mfma_f32_16x16x32_bf16(af[i], bf[j], acc[i][j], 0, 0, 0);
    }
    __syncthreads();
  }

#pragma unroll
  for (int i = 0; i < 2; i++)
#pragma unroll
    for (int j = 0; j < 2; j++) {
      const int rbase = m0 + wm * 32 + i * 16 + quad * 4;
      const int c = n0 + wn * 32 + j * 16 + l16;
#pragma unroll
      for (int r = 0; r < 4; r++) {
        const int row = rbase + r;
        if (c < 1024) {
          const float v = acc[i][j][r] + bu[c];
          ubuf[(long)row * 1024 + c] = 1.0f / (1.0f + expf(-v));
        } else {
          const int cc = c - 1024;
          const float v = acc[i][j][r] + br[cc];
          const float rr = 1.0f / (1.0f + expf(-v));
          candA[(long)row * 2048 + cc] =
              f2b(rr * b2f(conc[(long)row * 2048 + cc]));
        }
      }
    }
}

// ---------------- 64x64 MFMA GEMM, BK=64, dbuf, XCD-swizzled, K-splittable --
// K = PER-SLICE depth; blockIdx.z = k-slice. out: f32 partials.
__global__ __launch_bounds__(256) void k_gemm64(
    const unsigned short* __restrict__ A, int lda,
    const unsigned short* __restrict__ Bt, int ldb,
    int K, long sCk,
    float* __restrict__ out, int ldc) {
  __shared__ unsigned short As[2][64 * 64];
  __shared__ unsigned short Bs[2][64 * 64];
  const int tid = threadIdx.x;
  const int wave = tid >> 6, lane = tid & 63;
  const int kc = blockIdx.z;
  const long koff = (long)kc * K;
  const int flat = blockIdx.x + blockIdx.y * gridDim.x;
  const int q = (gridDim.x * gridDim.y) >> 3;
  const int swz = (flat & 7) * q + (flat >> 3);
  const int m0 = (swz % gridDim.x) * 64;
  const int n0 = (swz / gridDim.x) * 64;
  const int wm = wave & 1, wn = wave >> 1;
  const int l16 = lane & 15, quad = lane >> 4;
  const int srow8 = lane >> 3;
  const int c8 = ((lane & 7) ^ srow8) * 8;

  const unsigned short* gA[2];
  const unsigned short* gB[2];
  int lOff[2];
#pragma unroll
  for (int j = 0; j < 2; j++) {
    const int rb = wave * 16 + j * 8;
    gA[j] = A + (long)(m0 + rb + srow8) * lda + c8 + koff;
    gB[j] = Bt + (long)(n0 + rb + srow8) * ldb + c8 + koff;
    lOff[j] = rb * 64;
  }
  int offA[2][2], offB[2][2];
#pragma unroll
  for (int ks = 0; ks < 2; ks++)
#pragma unroll
    for (int i = 0; i < 2; i++) {
      int r = wm * 32 + i * 16 + l16;
      offA[ks][i] = r * 64 + (((ks * 4 + quad) ^ (r & 7)) * 8);
      r = wn * 32 + i * 16 + l16;
      offB[ks][i] = r * 64 + (((ks * 4 + quad) ^ (r & 7)) * 8);
    }

  floatx4 acc[2][2] = {};

#pragma unroll
  for (int j = 0; j < 2; j++) {
    g2l16(gA[j], &As[0][lOff[j]]);
    g2l16(gB[j], &Bs[0][lOff[j]]);
  }
  __syncthreads();

  const int nt = K >> 6;
  for (int t = 0; t < nt; t++) {
    const int cur = t & 1;
    if (t + 1 < nt) {
      const int kn = (t + 1) << 6;
#pragma unroll
      for (int j = 0; j < 2; j++) {
        g2l16(gA[j] + kn, &As[cur ^ 1][lOff[j]]);
        g2l16(gB[j] + kn, &Bs[cur ^ 1][lOff[j]]);
      }
    }
#pragma unroll
    for (int ks = 0; ks < 2; ks++) {
      shortx8 af[2], bf[2];
#pragma unroll
      for (int i = 0; i < 2; i++) af[i] = *(const shortx8*)&As[cur][offA[ks][i]];
#pragma unroll
      for (int j = 0; j < 2; j++) bf[j] = *(const shortx8*)&Bs[cur][offB[ks][j]];
#pragma unroll
      for (int i = 0; i < 2; i++)
#pragma unroll
        for (int j = 0; j < 2; j++)
          acc[i][j] = __builtin_amdgcn_mfma_f32_16x16x32_bf16(af[i], bf[j], acc[i][j], 0, 0, 0);
    }
    __syncthreads();
  }

#pragma unroll
  for (int i = 0; i < 2; i++)
#pragma unroll
    for (int j = 0; j < 2; j++) {
      const int rbase = m0 + wm * 32 + i * 16 + quad * 4;
      const int c = n0 + wn * 32 + j * 16 + l16;
#pragma unroll
      for (int r = 0; r < 4; r++)
        out[(long)kc * sCk + (long)(rbase + r) * ldc + c] = acc[i][j][r];
    }
}

// ---------------- proj2 (blocks 0..255) + prev-LN (blocks 256..1279) --------
__global__ __launch_bounds__(256) void k_proj2_ln(
    const float* __restrict__ P0, int lda,
    const unsigned short* __restrict__ Bt, int ldb,
    int K,
    const float* __restrict__ bp, const float* __restrict__ rowsum,
    float* __restrict__ out, int ldc,
    const float* __restrict__ prev,
    const float* __restrict__ g_st, const float* __restrict__ be_st,
    unsigned short* __restrict__ conc) {
  __shared__ unsigned short As[2][64 * 64];
  __shared__ unsigned short Bs[2][64 * 64];
  const int tid = threadIdx.x;
  if (blockIdx.x >= 256) {
    // ---- prev-LN
    float* scr = (float*)&As[0][0];
    const long r = blockIdx.x - 256;
    floatx4 v = *(const floatx4*)(prev + r * 1024 + tid * 4);
    float s1 = v[0] + v[1] + v[2] + v[3];
    float s2 = v[0] * v[0] + v[1] * v[1] + v[2] * v[2] + v[3] * v[3];
    s1 = block_sum(s1, scr);
    s2 = block_sum(s2, scr);
    const float mean = s1 * (1.0f / 1024.0f);
    const float var = s2 * (1.0f / 1024.0f) - mean * mean;
    const float rstd = rsqrtf(var + LN_EPS);
    unsigned short t4[4];
#pragma unroll
    for (int i = 0; i < 4; i++) {
      const int d = tid * 4 + i;
      t4[i] = f2b((v[i] - mean) * rstd * g_st[d] + be_st[d]);
    }
    *(uint2*)(conc + r * 2048 + tid * 4) = *(uint2*)t4;
    return;
  }
  // ---- proj2
  const int wave = tid >> 6, lane = tid & 63;
  const int flat = blockIdx.x;
  const int swz = (flat & 7) * 32 + (flat >> 3);  // bijective over 256
  const int m0 = (swz % 16) * 64;
  const int n0 = (swz / 16) * 64;
  const int wm = wave & 1, wn = wave >> 1;
  const int l16 = lane & 15, quad = lane >> 4;
  const int srow8 = lane >> 3;
  const int c8 = ((lane & 7) ^ srow8) * 8;

  const float* gAf[2];
  const unsigned short* gB[2];
  int lOff[2];
#pragma unroll
  for (int j = 0; j < 2; j++) {
    const int rb = wave * 16 + j * 8;
    gAf[j] = P0 + (long)(m0 + rb + srow8) * lda + c8;
    gB[j] = Bt + (long)(n0 + rb + srow8) * ldb + c8;
    lOff[j] = rb * 64;
  }
  int offA[2][2], offB[2][2];
#pragma unroll
  for (int ks = 0; ks < 2; ks++)
#pragma unroll
    for (int i = 0; i < 2; i++) {
      int r = wm * 32 + i * 16 + l16;
      offA[ks][i] = r * 64 + (((ks * 4 + quad) ^ (r & 7)) * 8);
      r = wn * 32 + i * 16 + l16;
      offB[ks][i] = r * 64 + (((ks * 4 + quad) ^ (r & 7)) * 8);
    }

  floatx4 acc[2][2] = {};

#pragma unroll
  for (int j = 0; j < 2; j++) {
    g2l16(gB[j], &Bs[0][lOff[j]]);
    floatx4 a0 = *(const floatx4*)(gAf[j]);
    floatx4 a1 = *(const floatx4*)(gAf[j] + 4);
    floatx4 b0 = *(const floatx4*)(gAf[j] + 786432);
    floatx4 b1 = *(const floatx4*)(gAf[j] + 786432 + 4);
    unsigned short t8[8];
#pragma unroll
    for (int i = 0; i < 4; i++) { t8[i] = f2b(a0[i] + b0[i]); t8[4 + i] = f2b(a1[i] + b1[i]); }
    *(uint4*)&As[0][lOff[j] + lane * 8] = *(uint4*)t8;
  }
  __syncthreads();

  const int nt = K >> 6;
  for (int t = 0; t < nt; t++) {
    const int cur = t & 1;
    floatx4 a0[2], a1[2], p0[2], p1[2];
    if (t + 1 < nt) {
      const int kn = (t + 1) << 6;
#pragma unroll
      for (int j = 0; j < 2; j++) {
        g2l16(gB[j] + kn, &Bs[cur ^ 1][lOff[j]]);
        a0[j] = *(const floatx4*)(gAf[j] + kn);
        a1[j] = *(const floatx4*)(gAf[j] + kn + 4);
        p0[j] = *(const floatx4*)(gAf[j] + kn + 786432);
        p1[j] = *(const floatx4*)(gAf[j] + kn + 786432 + 4);
      }
    }
#pragma unroll
    for (int ks = 0; ks < 2; ks++) {
      shortx8 af[2], bf[2];
#pragma unroll
      for (int i = 0; i < 2; i++) af[i] = *(const shortx8*)&As[cur][offA[ks][i]];
#pragma unroll
      for (int j = 0; j < 2; j++) bf[j] = *(const shortx8*)&Bs[cur][offB[ks][j]];
#pragma unroll
      for (int i = 0; i < 2; i++)
#pragma unroll
        for (int j = 0; j < 2; j++)
          acc[i][j] = __builtin_amdgcn_mfma_f32_16x16x32_bf16(af[i], bf[j], acc[i][j], 0, 0, 0);
    }
    if (t + 1 < nt) {
#pragma unroll
      for (int j = 0; j < 2; j++) {
        unsigned short t8[8];
#pragma unroll
        for (int i = 0; i < 4; i++) {
          t8[i] = f2b(a0[j][i] + p0[j][i]);
          t8[4 + i] = f2b(a1[j][i] + p1[j][i]);
        }
        *(uint4*)&As[cur ^ 1][lOff[j] + lane * 8] = *(uint4*)t8;
      }
    }
    __syncthreads();
  }

#pragma unroll
  for (int i = 0; i < 2; i++)
#pragma unroll
    for (int j = 0; j < 2; j++) {
      const int rbase = m0 + wm * 32 + i * 16 + quad * 4;
      const int c = n0 + wn * 32 + j * 16 + l16;
#pragma unroll
      for (int r = 0; r < 4; r++) {
        const int row = rbase + r;
        out[(long)row * ldc + c] = acc[i][j][r] + rowsum[row] * bp[c];
      }
    }
}

// ---------------- scores: A=pwb bf16 (g2l16), B=tokens f32 (reg-cvt) --------
__global__ __launch_bounds__(256) void k_scores(
    const unsigned short* __restrict__ A, long sAb, int lda,
    const float* __restrict__ toksf,
    int K, float scale,
    unsigned short* __restrict__ out2, int ldc, long sCb,
    float* __restrict__ rs) {
  __shared__ unsigned short As[2][64 * 64];
  __shared__ unsigned short Bs[2][64 * 64];
  const int tid = threadIdx.x;
  const int wave = tid >> 6, lane = tid & 63;
  const int b = blockIdx.z;
  const int m0 = 0, n0 = blockIdx.y * 64;
  const int wm = wave & 1, wn = wave >> 1;
  const int l16 = lane & 15, quad = lane >> 4;
  const int srow8 = lane >> 3;
  const int c8 = ((lane & 7) ^ srow8) * 8;
  const unsigned short* Ab = A + (long)b * sAb;

  const unsigned short* gA[2];
  const float* gBf[2];
  int lOff[2];
#pragma unroll
  for (int j = 0; j < 2; j++) {
    const int rb = wave * 16 + j * 8;
    gA[j] = Ab + (long)(m0 + rb + srow8) * lda + c8;
    gBf[j] = toksf + (long)b * 1572864 + (long)(n0 + rb + srow8) * 768 + c8;
    lOff[j] = rb * 64;
  }
  int offA[2][2], offB[2][2];
#pragma unroll
  for (int ks = 0; ks < 2; ks++)
#pragma unroll
    for (int i = 0; i < 2; i++) {
      int r = wm * 32 + i * 16 + l16;
      offA[ks][i] = r * 64 + (((ks * 4 + quad) ^ (r & 7)) * 8);
      r = wn * 32 + i * 16 + l16;
      offB[ks][i] = r * 64 + (((ks * 4 + quad) ^ (r & 7)) * 8);
    }

  floatx4 acc[2][2] = {};

#pragma unroll
  for (int j = 0; j < 2; j++) {
    g2l16(gA[j], &As[0][lOff[j]]);
    floatx4 v0 = *(const floatx4*)(gBf[j]);
    floatx4 v1 = *(const floatx4*)(gBf[j] + 4);
    unsigned short t8[8];
#pragma unroll
    for (int i = 0; i < 4; i++) { t8[i] = f2b(v0[i]); t8[4 + i] = f2b(v1[i]); }
    *(uint4*)&Bs[0][lOff[j] + lane * 8] = *(uint4*)t8;
  }
  __syncthreads();

  const int nt = K >> 6;
  for (int t = 0; t < nt; t++) {
    const int cur = t & 1;
    floatx4 w0[2], w1[2];
    if (t + 1 < nt) {
      const int kn = (t + 1) << 6;
#pragma unroll
      for (int j = 0; j < 2; j++) {
        g2l16(gA[j] + kn, &As[cur ^ 1][lOff[j]]);
        w0[j] = *(const floatx4*)(gBf[j] + kn);
        w1[j] = *(const floatx4*)(gBf[j] + kn + 4);
      }
    }
#pragma unroll
    for (int ks = 0; ks < 2; ks++) {
      shortx8 af[2], bf[2];
#pragma unroll
      for (int i = 0; i < 2; i++) af[i] = *(const shortx8*)&As[cur][offA[ks][i]];
#pragma unroll
      for (int j = 0; j < 2; j++) bf[j] = *(const shortx8*)&Bs[cur][offB[ks][j]];
#pragma unroll
      for (int i = 0; i < 2; i++)
#pragma unroll
        for (int j = 0; j < 2; j++)
          acc[i][j] = __builtin_amdgcn_mfma_f32_16x16x32_bf16(af[i], bf[j], acc[i][j], 0, 0, 0);
    }
    if (t + 1 < nt) {
#pragma unroll
      for (int j = 0; j < 2; j++) {
        unsigned short t8[8];
#pragma unroll
        for (int i = 0; i < 4; i++) { t8[i] = f2b(w0[j][i]); t8[4 + i] = f2b(w1[j][i]); }
        *(uint4*)&Bs[cur ^ 1][lOff[j] + lane * 8] = *(uint4*)t8;
      }
    }
    __syncthreads();
  }

#pragma unroll
  for (int i = 0; i < 2; i++) {
    float psum[4] = {0.f, 0.f, 0.f, 0.f};
#pragma unroll
    for (int j = 0; j < 2; j++) {
      const int rbase = m0 + wm * 32 + i * 16 + quad * 4;
      const int c = n0 + wn * 32 + j * 16 + l16;
#pragma unroll
      for (int r = 0; r < 4; r++) {
        const float e = expf(acc[i][j][r] * scale);
        out2[(long)b * sCb + (long)(rbase + r) * ldc + c] = f2b(e);
        psum[r] += e;
      }
    }
#pragma unroll
    for (int r = 0; r < 4; r++) {
      float s = psum[r];
      s += __shfl_xor(s, 1, 64);
      s += __shfl_xor(s, 2, 64);
      s += __shfl_xor(s, 4, 64);
      s += __shfl_xor(s, 8, 64);
      if (l16 == 0)
        atomicAdd(rs + (long)b * 64 + m0 + wm * 32 + i * 16 + quad * 4 + r, s);
    }
  }
}

// ---------------- rw = attnb(exp) @ tokens(f32) via MFMA, K-split x2 --------
__global__ __launch_bounds__(256) void k_routed_mfma(
    const unsigned short* __restrict__ attnb,
    const float* __restrict__ tokf,
    float* __restrict__ parts) {
  __shared__ unsigned short As[64 * 40];
  __shared__ unsigned short Bs[32 * 66];
  const int kc = blockIdx.x, nt = blockIdx.y, b = blockIdx.z;
  const int tid = threadIdx.x;
  const int wave = tid >> 6, lane = tid & 63;
  const int wm = wave & 1, wn = wave >> 1;
  const int l16 = lane & 15, quad = lane >> 4;
  const int n0 = nt * 64;
  const long abase = (long)b * 131072 + (long)kc * 1024;
  const long tbase = ((long)b * 2048 + (long)kc * 1024) * 768;
  const int srow = tid >> 2, skc = (tid & 3) * 8;
  const int bk = tid >> 3, bd = (tid & 7) * 8;

  floatx4 acc[2][2] = {};

  uint4 pa = *(const uint4*)(attnb + abase + (long)srow * 2048 + skc);
  floatx4 f0 = *(const floatx4*)(tokf + tbase + (long)bk * 768 + n0 + bd);
  floatx4 f1 = *(const floatx4*)(tokf + tbase + (long)bk * 768 + n0 + bd + 4);

  for (int k0 = 0; k0 < 1024; k0 += 32) {
    *(uint4*)&As[srow * 40 + skc] = pa;
    {
      unsigned short t8[8];
#pragma unroll
      for (int i = 0; i < 4; i++) { t8[i] = f2b(f0[i]); t8[4 + i] = f2b(f1[i]); }
      unsigned short* dst = &Bs[bk * 66 + bd];
#pragma unroll
      for (int w2 = 0; w2 < 4; w2++) *(unsigned*)(dst + w2 * 2) = ((unsigned*)t8)[w2];
    }
    if (k0 + 32 < 1024) {
      pa = *(const uint4*)(attnb + abase + (long)srow * 2048 + (k0 + 32) + skc);
      f0 = *(const floatx4*)(tokf + tbase + (long)(k0 + 32 + bk) * 768 + n0 + bd);
      f1 = *(const floatx4*)(tokf + tbase + (long)(k0 + 32 + bk) * 768 + n0 + bd + 4);
    }
    asm volatile("s_waitcnt lgkmcnt(0)" ::: "memory");
    __builtin_amdgcn_s_barrier();
    __builtin_amdgcn_sched_barrier(0);

    shortx8 a0 = *(const shortx8*)&As[(wm * 32 + 0  + l16) * 40 + quad * 8];
    shortx8 a1 = *(const shortx8*)&As[(wm * 32 + 16 + l16) * 40 + quad * 8];
    shortx8 b0, b1;
#pragma unroll
    for (int j = 0; j < 8; j++) {
      b0[j] = *(const short*)&Bs[(quad * 8 + j) * 66 + wn * 32 + l16];
      b1[j] = *(const short*)&Bs[(quad * 8 + j) * 66 + wn * 32 + 16 + l16];
    }
    acc[0][0] = __builtin_amdgcn_mfma_f32_16x16x32_bf16(a0, b0, acc[0][0], 0, 0, 0);
    acc[0][1] = __builtin_amdgcn_mfma_f32_16x16x32_bf16(a0, b1, acc[0][1], 0, 0, 0);
    acc[1][0] = __builtin_amdgcn_mfma_f32_16x16x32_bf16(a1, b0, acc[1][0], 0, 0, 0);
    acc[1][1] = __builtin_amdgcn_mfma_f32_16x16x32_bf16(a1, b1, acc[1][1], 0, 0, 0);
    __builtin_amdgcn_s_barrier();
  }

#pragma unroll
  for (int im = 0; im < 2; im++)
#pragma unroll
    for (int in_ = 0; in_ < 2; in_++) {
      const int rbase = wm * 32 + im * 16 + quad * 4;
      const int c = n0 + wn * 32 + in_ * 16 + l16;
#pragma unroll
      for (int r = 0; r < 4; r++)
        parts[(long)kc * 786432 + ((long)b * 64 + rbase + r) * 768 + c] =
            acc[im][in_][r];
    }
}

// ---------------- routed LayerNorm -> conc second half + candA second half --
__global__ __launch_bounds__(256) void k_ln_routed(
    const float* __restrict__ routed,
    const float* __restrict__ g_in, const float* __restrict__ be_in,
    unsigned short* __restrict__ conc, unsigned short* __restrict__ candA) {
  __shared__ float scr[4];
  const long r = blockIdx.x;
  const int t = threadIdx.x;
  floatx4 v = *(const floatx4*)(routed + r * 1024 + t * 4);
  float s1 = v[0] + v[1] + v[2] + v[3];
  float s2 = v[0] * v[0] + v[1] * v[1] + v[2] * v[2] + v[3] * v[3];
  s1 = block_sum(s1, scr);
  s2 = block_sum(s2, scr);
  const float mean = s1 * (1.0f / 1024.0f);
  const float var = s2 * (1.0f / 1024.0f) - mean * mean;
  const float rstd = rsqrtf(var + LN_EPS);
  unsigned short t4[4];
#pragma unroll
  for (int i = 0; i < 4; i++) {
    const int d = t * 4 + i;
    t4[i] = f2b((v[i] - mean) * rstd * g_in[d] + be_in[d]);
  }
  *(uint2*)(conc + r * 2048 + 1024 + t * 4) = *(uint2*)t4;
  *(uint2*)(candA + r * 2048 + 1024 + t * 4) = *(uint2*)t4;
}

// ---------------- final: cand-epilogue + LayerNorm -> f32 output ------------
__global__ __launch_bounds__(256) void k_ln_out(
    const float* __restrict__ cparts,  // [2][1024][1024]
    const float* __restrict__ ubuf, const float* __restrict__ prev,
    const float* __restrict__ bn,
    const float* __restrict__ g, const float* __restrict__ be,
    float* __restrict__ out) {
  __shared__ float scr[4];
  const long r = blockIdx.x;
  const int t = threadIdx.x;
  floatx4 p0 = *(const floatx4*)(cparts + r * 1024 + t * 4);
  floatx4 p1 = *(const floatx4*)(cparts + 1048576 + r * 1024 + t * 4);
  floatx4 uu = *(const floatx4*)(ubuf + r * 1024 + t * 4);
  floatx4 pv = *(const floatx4*)(prev + r * 1024 + t * 4);
  floatx4 bv = *(const floatx4*)(bn + t * 4);
  floatx4 v;
#pragma unroll
  for (int i = 0; i < 4; i++) {
    const float cand = tanhf(p0[i] + p1[i] + bv[i]);
    v[i] = (1.0f - uu[i]) * pv[i] + uu[i] * cand;
  }
  float s1 = v[0] + v[1] + v[2] + v[3];
  float s2 = v[0] * v[0] + v[1] * v[1] + v[2] * v[2] + v[3] * v[3];
  s1 = block_sum(s1, scr);
  s2 = block_sum(s2, scr);
  const float mean = s1 * (1.0f / 1024.0f);
  const float var = s2 * (1.0f / 1024.0f) - mean * mean;
  const float rstd = rsqrtf(var + LN_EPS);
  floatx4 o;
#pragma unroll
  for (int i = 0; i < 4; i++) {
    const int d = t * 4 + i;
    o[i] = (v[i] - mean) * rstd * g[d] + be[d];
  }
  *(floatx4*)(out + r * 1024 + t * 4) = o;
}

// ---------------------------------------------------------------------------
extern "C" void kernel_launch(void* const* d_in, const int* in_sizes, int n_in,
                              void* d_out, int out_size, void* d_ws, size_t ws_size,
                              hipStream_t stream) {
  (void)in_sizes; (void)n_in; (void)out_size; (void)ws_size;
  const float* prev  = (const float*)d_in[0];
  const float* toks  = (const float*)d_in[1];
  const float* Wp    = (const float*)d_in[2];
  const float* bp    = (const float*)d_in[3];
  const float* g_st  = (const float*)d_in[4];
  const float* be_st = (const float*)d_in[5];
  const float* g_in  = (const float*)d_in[6];
  const float* be_in = (const float*)d_in[7];
  const float* g_o   = (const float*)d_in[8];
  const float* be_o  = (const float*)d_in[9];
  const float* Wu    = (const float*)d_in[10];
  const float* bu    = (const float*)d_in[11];
  const float* Wr    = (const float*)d_in[12];
  const float* br    = (const float*)d_in[13];
  const float* Wn    = (const float*)d_in[14];
  const float* bn    = (const float*)d_in[15];
  float* out = (float*)d_out;

  // ---- workspace (~54 MB)
  char* ws = (char*)d_ws;
  unsigned short* Wtp   = (unsigned short*)ws; ws += 1572864;   // 1024x768 bf16
  unsigned short* pwb   = (unsigned short*)ws; ws += 1572864;   // 1024x768 bf16
  unsigned short* attnb = (unsigned short*)ws; ws += 4194304;   // 16x64x2048 bf16
  float*          rowsum= (float*)ws;          ws += 4096;      // 1024 f32
  float*          parts = (float*)ws;          ws += 6291456;   // 2x 1024x768 f32
  float*          routed= (float*)ws;          ws += 4194304;   // 1024x1024 f32
  unsigned short* conc  = (unsigned short*)ws; ws += 4194304;   // 1024x2048 bf16
  unsigned short* candA = (unsigned short*)ws; ws += 4194304;   // 1024x2048 bf16
  float*          ubuf  = (float*)ws;          ws += 4194304;   // 1024x1024 f32
  unsigned short* Wtur  = (unsigned short*)ws; ws += 8388608;   // 2048x2048 bf16
  unsigned short* Wtn   = (unsigned short*)ws; ws += 4194304;   // 1024x2048 bf16
  float*          cparts= (float*)ws;          ws += 8388608;   // 2x 1024x1024 f32

  const dim3 blk(256);

  // 1. merged: pw GEMM (f32-direct) + 4 transposes + rowsum zero
  k_prep_pw<<<dim3(7104), blk, 0, stream>>>(prev, Wp, Wu, Wr, Wn,
                                            Wtur, Wtn, Wtp, pwb, rowsum);
  // 2. attnb = exp(pw @ tokens^T / 32) + fused rowsum atomics, 512 blocks
  k_scores<<<dim3(1, 32, 16), blk, 0, stream>>>(
      pwb, 49152L, 768, toks, 768, 0.03125f,
      attnb, 2048, 131072L, rowsum);
  // 3. rw partials = w @ tokens(f32), K-split x2, 384 blocks
  k_routed_mfma<<<dim3(2, 12, 16), blk, 0, stream>>>(attnb, toks, parts);
  // 4. merged: proj2 (256 blocks) + prev-LN (1024 blocks)
  k_proj2_ln<<<dim3(1280), blk, 0, stream>>>(
      parts, 768, Wtp, 768, 768, bp, rowsum, routed, 1024,
      prev, g_st, be_st, conc);
  // 5. routed LN -> conc/candA second halves
  k_ln_routed<<<dim3(1024), blk, 0, stream>>>(routed, g_in, be_in, conc, candA);
  // 6. gates GEMM K=2048 unsplit, fused sigmoid epilogue (u -> ubuf,
  //    r*ps_n -> candA first half), 512 blocks
  k_gates5<<<dim3(16, 32), blk, 0, stream>>>(conc, Wtur, bu, br, ubuf, candA);
  // 7. cand GEMM, K-split x2 (f32 partials), 512 blocks
  k_gemm64<<<dim3(16, 16, 2), blk, 0, stream>>>(
      candA, 2048, Wtn, 2048, 1024, 1048576L, cparts, 1024);
  // 8. fused cand-epilogue + final LN -> output
  k_ln_out<<<dim3(1024), blk, 0, stream>>>(cparts, ubuf, prev, bn, g_o, be_o, out);
}

// Round 12
// 295.195 us; speedup vs baseline: 1.0253x; 1.0187x over previous
//
#include <hip/hip_runtime.h>
#include <stdint.h>

typedef __attribute__((ext_vector_type(4))) float floatx4;
typedef __attribute__((ext_vector_type(8))) short shortx8;

#define LN_EPS 1e-5f

__device__ __forceinline__ unsigned short f2b(float f) {
  unsigned u = __builtin_bit_cast(unsigned, f);
  u = (u + 0x7FFFu + ((u >> 16) & 1u)) >> 16;
  return (unsigned short)u;
}
__device__ __forceinline__ float b2f(unsigned short h) {
  return __builtin_bit_cast(float, (unsigned)h << 16);
}

// async global->LDS 16B: lds dest is wave-uniform base; lane i lands at base + i*16
__device__ __forceinline__ void g2l16(const unsigned short* g, unsigned short* l) {
  __builtin_amdgcn_global_load_lds(
      (const __attribute__((address_space(1))) unsigned int*)g,
      (__attribute__((address_space(3))) unsigned int*)l, 16, 0, 0);
}

// ---------------- block reduction helpers (256 threads = 4 waves) -----------
__device__ __forceinline__ float wave_sum(float v) {
#pragma unroll
  for (int o = 32; o; o >>= 1) v += __shfl_down(v, o, 64);
  return v;
}
__device__ __forceinline__ float block_sum(float v, float* s) {
  v = wave_sum(v);
  __syncthreads();
  if ((threadIdx.x & 63) == 0) s[threadIdx.x >> 6] = v;
  __syncthreads();
  return s[0] + s[1] + s[2] + s[3];
}

// ---------------- merged: pw GEMM (blocks 0..191) + transposes + rowsum -----
__global__ __launch_bounds__(256) void k_prep_pw(
    const float* __restrict__ prev, const float* __restrict__ wp,
    const float* __restrict__ Wu, const float* __restrict__ Wr,
    const float* __restrict__ Wn,
    unsigned short* __restrict__ Wtur, unsigned short* __restrict__ Wtn,
    unsigned short* __restrict__ Wtp, unsigned short* __restrict__ pwb,
    float* __restrict__ rs) {
  __shared__ unsigned short As[2][64 * 64];
  __shared__ unsigned short Bs[2][64 * 64];
  const int bid = blockIdx.x;
  const int tid = threadIdx.x;
  if (bid < 192) {
    const int wave = tid >> 6, lane = tid & 63;
    const int swz = (bid & 7) * 24 + (bid >> 3);  // XCD-bijective over 192
    const int m0 = (swz % 16) * 64;
    const int n0 = (swz / 16) * 64;
    const int wm = wave & 1, wn = wave >> 1;
    const int l16 = lane & 15, quad = lane >> 4;
    const int srow8 = lane >> 3;
    const int c8 = ((lane & 7) ^ srow8) * 8;

    const float* gAf[2];
    const float* gBf[2];
    int lOff[2];
#pragma unroll
    for (int j = 0; j < 2; j++) {
      const int rb = wave * 16 + j * 8;
      gAf[j] = prev + (long)(m0 + rb + srow8) * 1024 + c8;
      gBf[j] = wp + (long)(n0 + rb + srow8) * 1024 + c8;
      lOff[j] = rb * 64;
    }
    int offA[2][2], offB[2][2];
#pragma unroll
    for (int ks = 0; ks < 2; ks++)
#pragma unroll
      for (int i = 0; i < 2; i++) {
        int r = wm * 32 + i * 16 + l16;
        offA[ks][i] = r * 64 + (((ks * 4 + quad) ^ (r & 7)) * 8);
        r = wn * 32 + i * 16 + l16;
        offB[ks][i] = r * 64 + (((ks * 4 + quad) ^ (r & 7)) * 8);
      }

    floatx4 acc[2][2] = {};

#pragma unroll
    for (int j = 0; j < 2; j++) {
      floatx4 a0 = *(const floatx4*)(gAf[j]);
      floatx4 a1 = *(const floatx4*)(gAf[j] + 4);
      floatx4 b0 = *(const floatx4*)(gBf[j]);
      floatx4 b1 = *(const floatx4*)(gBf[j] + 4);
      unsigned short ta[8], tb[8];
#pragma unroll
      for (int i = 0; i < 4; i++) {
        ta[i] = f2b(a0[i]); ta[4 + i] = f2b(a1[i]);
        tb[i] = f2b(b0[i]); tb[4 + i] = f2b(b1[i]);
      }
      *(uint4*)&As[0][lOff[j] + lane * 8] = *(uint4*)ta;
      *(uint4*)&Bs[0][lOff[j] + lane * 8] = *(uint4*)tb;
    }
    __syncthreads();

    const int nt = 16;
    for (int t = 0; t < nt; t++) {
      const int cur = t & 1;
      floatx4 a0[2], a1[2], b0[2], b1[2];
      if (t + 1 < nt) {
        const int kn = (t + 1) << 6;
#pragma unroll
        for (int j = 0; j < 2; j++) {
          a0[j] = *(const floatx4*)(gAf[j] + kn);
          a1[j] = *(const floatx4*)(gAf[j] + kn + 4);
          b0[j] = *(const floatx4*)(gBf[j] + kn);
          b1[j] = *(const floatx4*)(gBf[j] + kn + 4);
        }
      }
#pragma unroll
      for (int ks = 0; ks < 2; ks++) {
        shortx8 af[2], bf[2];
#pragma unroll
        for (int i = 0; i < 2; i++) af[i] = *(const shortx8*)&As[cur][offA[ks][i]];
#pragma unroll
        for (int j = 0; j < 2; j++) bf[j] = *(const shortx8*)&Bs[cur][offB[ks][j]];
#pragma unroll
        for (int i = 0; i < 2; i++)
#pragma unroll
          for (int j = 0; j < 2; j++)
            acc[i][j] = __builtin_amdgcn_mfma_f32_16x16x32_bf16(af[i], bf[j], acc[i][j], 0, 0, 0);
      }
      if (t + 1 < nt) {
#pragma unroll
        for (int j = 0; j < 2; j++) {
          unsigned short ta[8], tb[8];
#pragma unroll
          for (int i = 0; i < 4; i++) {
            ta[i] = f2b(a0[j][i]); ta[4 + i] = f2b(a1[j][i]);
            tb[i] = f2b(b0[j][i]); tb[4 + i] = f2b(b1[j][i]);
          }
          *(uint4*)&As[cur ^ 1][lOff[j] + lane * 8] = *(uint4*)ta;
          *(uint4*)&Bs[cur ^ 1][lOff[j] + lane * 8] = *(uint4*)tb;
        }
      }
      __syncthreads();
    }

#pragma unroll
    for (int i = 0; i < 2; i++)
#pragma unroll
      for (int j = 0; j < 2; j++) {
        const int rbase = m0 + wm * 32 + i * 16 + quad * 4;
        const int c = n0 + wn * 32 + j * 16 + l16;
#pragma unroll
        for (int r = 0; r < 4; r++)
          pwb[(long)(rbase + r) * 768 + c] = f2b(acc[i][j][r]);
      }
    return;
  }
  // ---- transpose part (aliases LDS)
  float(*tile)[33] = (float(*)[33]) & As[0][0];
  if (bid == 192) {
    floatx4 z = {0.f, 0.f, 0.f, 0.f};
    *(floatx4*)(rs + tid * 4) = z;
  }
  int t = bid - 192;
  const float* in;
  unsigned short* out;
  int K, kx, ny;
  if (t < 6144) {
    const int which = t >> 11;
    const int t2 = t & 2047;
    kx = t2 & 63;
    ny = t2 >> 6;
    K = 2048;
    in = which == 0 ? Wu : (which == 1 ? Wr : Wn);
    out = which == 0 ? Wtur : (which == 1 ? Wtur + 1024 * 2048 : Wtn);
  } else {
    const int t2 = t - 6144;
    kx = t2 % 24;
    ny = t2 / 24;
    K = 768;
    in = wp;
    out = Wtp;
  }
  const int N = 1024;
  const int k0 = kx * 32, n0 = ny * 32;
  const int tx = tid & 31, ty = tid >> 5;
#pragma unroll
  for (int i = 0; i < 32; i += 8)
    tile[ty + i][tx] = in[(long)(k0 + ty + i) * N + n0 + tx];
  __syncthreads();
#pragma unroll
  for (int i = 0; i < 32; i += 8)
    out[(long)(n0 + ty + i) * K + k0 + tx] = f2b(tile[tx][ty + i]);
}

// ---------------- 64x64 MFMA GEMM, BK=64, dbuf, XCD-swizzled, K-splittable --
// K = PER-SLICE depth; blockIdx.z = k-slice. out: f32 partials.
__global__ __launch_bounds__(256) void k_gemm64(
    const unsigned short* __restrict__ A, int lda,
    const unsigned short* __restrict__ Bt, int ldb,
    int K, long sCk,
    float* __restrict__ out, int ldc) {
  __shared__ unsigned short As[2][64 * 64];
  __shared__ unsigned short Bs[2][64 * 64];
  const int tid = threadIdx.x;
  const int wave = tid >> 6, lane = tid & 63;
  const int kc = blockIdx.z;
  const long koff = (long)kc * K;
  const int flat = blockIdx.x + blockIdx.y * gridDim.x;
  const int q = (gridDim.x * gridDim.y) >> 3;
  const int swz = (flat & 7) * q + (flat >> 3);
  const int m0 = (swz % gridDim.x) * 64;
  const int n0 = (swz / gridDim.x) * 64;
  const int wm = wave & 1, wn = wave >> 1;
  const int l16 = lane & 15, quad = lane >> 4;
  const int srow8 = lane >> 3;
  const int c8 = ((lane & 7) ^ srow8) * 8;

  const unsigned short* gA[2];
  const unsigned short* gB[2];
  int lOff[2];
#pragma unroll
  for (int j = 0; j < 2; j++) {
    const int rb = wave * 16 + j * 8;
    gA[j] = A + (long)(m0 + rb + srow8) * lda + c8 + koff;
    gB[j] = Bt + (long)(n0 + rb + srow8) * ldb + c8 + koff;
    lOff[j] = rb * 64;
  }
  int offA[2][2], offB[2][2];
#pragma unroll
  for (int ks = 0; ks < 2; ks++)
#pragma unroll
    for (int i = 0; i < 2; i++) {
      int r = wm * 32 + i * 16 + l16;
      offA[ks][i] = r * 64 + (((ks * 4 + quad) ^ (r & 7)) * 8);
      r = wn * 32 + i * 16 + l16;
      offB[ks][i] = r * 64 + (((ks * 4 + quad) ^ (r & 7)) * 8);
    }

  floatx4 acc[2][2] = {};

#pragma unroll
  for (int j = 0; j < 2; j++) {
    g2l16(gA[j], &As[0][lOff[j]]);
    g2l16(gB[j], &Bs[0][lOff[j]]);
  }
  __syncthreads();

  const int nt = K >> 6;
  for (int t = 0; t < nt; t++) {
    const int cur = t & 1;
    if (t + 1 < nt) {
      const int kn = (t + 1) << 6;
#pragma unroll
      for (int j = 0; j < 2; j++) {
        g2l16(gA[j] + kn, &As[cur ^ 1][lOff[j]]);
        g2l16(gB[j] + kn, &Bs[cur ^ 1][lOff[j]]);
      }
    }
#pragma unroll
    for (int ks = 0; ks < 2; ks++) {
      shortx8 af[2], bf[2];
#pragma unroll
      for (int i = 0; i < 2; i++) af[i] = *(const shortx8*)&As[cur][offA[ks][i]];
#pragma unroll
      for (int j = 0; j < 2; j++) bf[j] = *(const shortx8*)&Bs[cur][offB[ks][j]];
#pragma unroll
      for (int i = 0; i < 2; i++)
#pragma unroll
        for (int j = 0; j < 2; j++)
          acc[i][j] = __builtin_amdgcn_mfma_f32_16x16x32_bf16(af[i], bf[j], acc[i][j], 0, 0, 0);
    }
    __syncthreads();
  }

#pragma unroll
  for (int i = 0; i < 2; i++)
#pragma unroll
    for (int j = 0; j < 2; j++) {
      const int rbase = m0 + wm * 32 + i * 16 + quad * 4;
      const int c = n0 + wn * 32 + j * 16 + l16;
#pragma unroll
      for (int r = 0; r < 4; r++)
        out[(long)kc * sCk + (long)(rbase + r) * ldc + c] = acc[i][j][r];
    }
}

// ---------------- proj2 (blocks 0..255) + prev-LN (blocks 256..1279) --------
__global__ __launch_bounds__(256) void k_proj2_ln(
    const float* __restrict__ P0, int lda,
    const unsigned short* __restrict__ Bt, int ldb,
    int K,
    const float* __restrict__ bp, const float* __restrict__ rowsum,
    float* __restrict__ out, int ldc,
    const float* __restrict__ prev,
    const float* __restrict__ g_st, const float* __restrict__ be_st,
    unsigned short* __restrict__ conc) {
  __shared__ unsigned short As[2][64 * 64];
  __shared__ unsigned short Bs[2][64 * 64];
  const int tid = threadIdx.x;
  if (blockIdx.x >= 256) {
    // ---- prev-LN
    float* scr = (float*)&As[0][0];
    const long r = blockIdx.x - 256;
    floatx4 v = *(const floatx4*)(prev + r * 1024 + tid * 4);
    float s1 = v[0] + v[1] + v[2] + v[3];
    float s2 = v[0] * v[0] + v[1] * v[1] + v[2] * v[2] + v[3] * v[3];
    s1 = block_sum(s1, scr);
    s2 = block_sum(s2, scr);
    const float mean = s1 * (1.0f / 1024.0f);
    const float var = s2 * (1.0f / 1024.0f) - mean * mean;
    const float rstd = rsqrtf(var + LN_EPS);
    unsigned short t4[4];
#pragma unroll
    for (int i = 0; i < 4; i++) {
      const int d = tid * 4 + i;
      t4[i] = f2b((v[i] - mean) * rstd * g_st[d] + be_st[d]);
    }
    *(uint2*)(conc + r * 2048 + tid * 4) = *(uint2*)t4;
    return;
  }
  // ---- proj2
  const int wave = tid >> 6, lane = tid & 63;
  const int flat = blockIdx.x;
  const int swz = (flat & 7) * 32 + (flat >> 3);  // bijective over 256
  const int m0 = (swz % 16) * 64;
  const int n0 = (swz / 16) * 64;
  const int wm = wave & 1, wn = wave >> 1;
  const int l16 = lane & 15, quad = lane >> 4;
  const int srow8 = lane >> 3;
  const int c8 = ((lane & 7) ^ srow8) * 8;

  const float* gAf[2];
  const unsigned short* gB[2];
  int lOff[2];
#pragma unroll
  for (int j = 0; j < 2; j++) {
    const int rb = wave * 16 + j * 8;
    gAf[j] = P0 + (long)(m0 + rb + srow8) * lda + c8;
    gB[j] = Bt + (long)(n0 + rb + srow8) * ldb + c8;
    lOff[j] = rb * 64;
  }
  int offA[2][2], offB[2][2];
#pragma unroll
  for (int ks = 0; ks < 2; ks++)
#pragma unroll
    for (int i = 0; i < 2; i++) {
      int r = wm * 32 + i * 16 + l16;
      offA[ks][i] = r * 64 + (((ks * 4 + quad) ^ (r & 7)) * 8);
      r = wn * 32 + i * 16 + l16;
      offB[ks][i] = r * 64 + (((ks * 4 + quad) ^ (r & 7)) * 8);
    }

  floatx4 acc[2][2] = {};

#pragma unroll
  for (int j = 0; j < 2; j++) {
    g2l16(gB[j], &Bs[0][lOff[j]]);
    floatx4 a0 = *(const floatx4*)(gAf[j]);
    floatx4 a1 = *(const floatx4*)(gAf[j] + 4);
    floatx4 b0 = *(const floatx4*)(gAf[j] + 786432);
    floatx4 b1 = *(const floatx4*)(gAf[j] + 786432 + 4);
    unsigned short t8[8];
#pragma unroll
    for (int i = 0; i < 4; i++) { t8[i] = f2b(a0[i] + b0[i]); t8[4 + i] = f2b(a1[i] + b1[i]); }
    *(uint4*)&As[0][lOff[j] + lane * 8] = *(uint4*)t8;
  }
  __syncthreads();

  const int nt = K >> 6;
  for (int t = 0; t < nt; t++) {
    const int cur = t & 1;
    floatx4 a0[2], a1[2], p0[2], p1[2];
    if (t + 1 < nt) {
      const int kn = (t + 1) << 6;
#pragma unroll
      for (int j = 0; j < 2; j++) {
        g2l16(gB[j] + kn, &Bs[cur ^ 1][lOff[j]]);
        a0[j] = *(const floatx4*)(gAf[j] + kn);
        a1[j] = *(const floatx4*)(gAf[j] + kn + 4);
        p0[j] = *(const floatx4*)(gAf[j] + kn + 786432);
        p1[j] = *(const floatx4*)(gAf[j] + kn + 786432 + 4);
      }
    }
#pragma unroll
    for (int ks = 0; ks < 2; ks++) {
      shortx8 af[2], bf[2];
#pragma unroll
      for (int i = 0; i < 2; i++) af[i] = *(const shortx8*)&As[cur][offA[ks][i]];
#pragma unroll
      for (int j = 0; j < 2; j++) bf[j] = *(const shortx8*)&Bs[cur][offB[ks][j]];
#pragma unroll
      for (int i = 0; i < 2; i++)
#pragma unroll
        for (int j = 0; j < 2; j++)
          acc[i][j] = __builtin_amdgcn_mfma_f32_16x16x32_bf16(af[i], bf[j], acc[i][j], 0, 0, 0);
    }
    if (t + 1 < nt) {
#pragma unroll
      for (int j = 0; j < 2; j++) {
        unsigned short t8[8];
#pragma unroll
        for (int i = 0; i < 4; i++) {
          t8[i] = f2b(a0[j][i] + p0[j][i]);
          t8[4 + i] = f2b(a1[j][i] + p1[j][i]);
        }
        *(uint4*)&As[cur ^ 1][lOff[j] + lane * 8] = *(uint4*)t8;
      }
    }
    __syncthreads();
  }

#pragma unroll
  for (int i = 0; i < 2; i++)
#pragma unroll
    for (int j = 0; j < 2; j++) {
      const int rbase = m0 + wm * 32 + i * 16 + quad * 4;
      const int c = n0 + wn * 32 + j * 16 + l16;
#pragma unroll
      for (int r = 0; r < 4; r++) {
        const int row = rbase + r;
        out[(long)row * ldc + c] = acc[i][j][r] + rowsum[row] * bp[c];
      }
    }
}

// ---------------- scores: A=pwb bf16 (g2l16), B=tokens f32 (reg-cvt) --------
__global__ __launch_bounds__(256) void k_scores(
    const unsigned short* __restrict__ A, long sAb, int lda,
    const float* __restrict__ toksf,
    int K, float scale,
    unsigned short* __restrict__ out2, int ldc, long sCb,
    float* __restrict__ rs) {
  __shared__ unsigned short As[2][64 * 64];
  __shared__ unsigned short Bs[2][64 * 64];
  const int tid = threadIdx.x;
  const int wave = tid >> 6, lane = tid & 63;
  const int b = blockIdx.z;
  const int m0 = 0, n0 = blockIdx.y * 64;
  const int wm = wave & 1, wn = wave >> 1;
  const int l16 = lane & 15, quad = lane >> 4;
  const int srow8 = lane >> 3;
  const int c8 = ((lane & 7) ^ srow8) * 8;
  const unsigned short* Ab = A + (long)b * sAb;

  const unsigned short* gA[2];
  const float* gBf[2];
  int lOff[2];
#pragma unroll
  for (int j = 0; j < 2; j++) {
    const int rb = wave * 16 + j * 8;
    gA[j] = Ab + (long)(m0 + rb + srow8) * lda + c8;
    gBf[j] = toksf + (long)b * 1572864 + (long)(n0 + rb + srow8) * 768 + c8;
    lOff[j] = rb * 64;
  }
  int offA[2][2], offB[2][2];
#pragma unroll
  for (int ks = 0; ks < 2; ks++)
#pragma unroll
    for (int i = 0; i < 2; i++) {
      int r = wm * 32 + i * 16 + l16;
      offA[ks][i] = r * 64 + (((ks * 4 + quad) ^ (r & 7)) * 8);
      r = wn * 32 + i * 16 + l16;
      offB[ks][i] = r * 64 + (((ks * 4 + quad) ^ (r & 7)) * 8);
    }

  floatx4 acc[2][2] = {};

#pragma unroll
  for (int j = 0; j < 2; j++) {
    g2l16(gA[j], &As[0][lOff[j]]);
    floatx4 v0 = *(const floatx4*)(gBf[j]);
    floatx4 v1 = *(const floatx4*)(gBf[j] + 4);
    unsigned short t8[8];
#pragma unroll
    for (int i = 0; i < 4; i++) { t8[i] = f2b(v0[i]); t8[4 + i] = f2b(v1[i]); }
    *(uint4*)&Bs[0][lOff[j] + lane * 8] = *(uint4*)t8;
  }
  __syncthreads();

  const int nt = K >> 6;
  for (int t = 0; t < nt; t++) {
    const int cur = t & 1;
    floatx4 w0[2], w1[2];
    if (t + 1 < nt) {
      const int kn = (t + 1) << 6;
#pragma unroll
      for (int j = 0; j < 2; j++) {
        g2l16(gA[j] + kn, &As[cur ^ 1][lOff[j]]);
        w0[j] = *(const floatx4*)(gBf[j] + kn);
        w1[j] = *(const floatx4*)(gBf[j] + kn + 4);
      }
    }
#pragma unroll
    for (int ks = 0; ks < 2; ks++) {
      shortx8 af[2], bf[2];
#pragma unroll
      for (int i = 0; i < 2; i++) af[i] = *(const shortx8*)&As[cur][offA[ks][i]];
#pragma unroll
      for (int j = 0; j < 2; j++) bf[j] = *(const shortx8*)&Bs[cur][offB[ks][j]];
#pragma unroll
      for (int i = 0; i < 2; i++)
#pragma unroll
        for (int j = 0; j < 2; j++)
          acc[i][j] = __builtin_amdgcn_mfma_f32_16x16x32_bf16(af[i], bf[j], acc[i][j], 0, 0, 0);
    }
    if (t + 1 < nt) {
#pragma unroll
      for (int j = 0; j < 2; j++) {
        unsigned short t8[8];
#pragma unroll
        for (int i = 0; i < 4; i++) { t8[i] = f2b(w0[j][i]); t8[4 + i] = f2b(w1[j][i]); }
        *(uint4*)&Bs[cur ^ 1][lOff[j] + lane * 8] = *(uint4*)t8;
      }
    }
    __syncthreads();
  }

#pragma unroll
  for (int i = 0; i < 2; i++) {
    float psum[4] = {0.f, 0.f, 0.f, 0.f};
#pragma unroll
    for (int j = 0; j < 2; j++) {
      const int rbase = m0 + wm * 32 + i * 16 + quad * 4;
      const int c = n0 + wn * 32 + j * 16 + l16;
#pragma unroll
      for (int r = 0; r < 4; r++) {
        const float e = expf(acc[i][j][r] * scale);
        out2[(long)b * sCb + (long)(rbase + r) * ldc + c] = f2b(e);
        psum[r] += e;
      }
    }
#pragma unroll
    for (int r = 0; r < 4; r++) {
      float s = psum[r];
      s += __shfl_xor(s, 1, 64);
      s += __shfl_xor(s, 2, 64);
      s += __shfl_xor(s, 4, 64);
      s += __shfl_xor(s, 8, 64);
      if (l16 == 0)
        atomicAdd(rs + (long)b * 64 + m0 + wm * 32 + i * 16 + quad * 4 + r, s);
    }
  }
}

// ---------------- rw = attnb(exp) @ tokens(f32) via MFMA, K-split x2 --------
__global__ __launch_bounds__(256) void k_routed_mfma(
    const unsigned short* __restrict__ attnb,
    const float* __restrict__ tokf,
    float* __restrict__ parts) {
  __shared__ unsigned short As[64 * 40];
  __shared__ unsigned short Bs[32 * 66];
  const int kc = blockIdx.x, nt = blockIdx.y, b = blockIdx.z;
  const int tid = threadIdx.x;
  const int wave = tid >> 6, lane = tid & 63;
  const int wm = wave & 1, wn = wave >> 1;
  const int l16 = lane & 15, quad = lane >> 4;
  const int n0 = nt * 64;
  const long abase = (long)b * 131072 + (long)kc * 1024;
  const long tbase = ((long)b * 2048 + (long)kc * 1024) * 768;
  const int srow = tid >> 2, skc = (tid & 3) * 8;
  const int bk = tid >> 3, bd = (tid & 7) * 8;

  floatx4 acc[2][2] = {};

  uint4 pa = *(const uint4*)(attnb + abase + (long)srow * 2048 + skc);
  floatx4 f0 = *(const floatx4*)(tokf + tbase + (long)bk * 768 + n0 + bd);
  floatx4 f1 = *(const floatx4*)(tokf + tbase + (long)bk * 768 + n0 + bd + 4);

  for (int k0 = 0; k0 < 1024; k0 += 32) {
    *(uint4*)&As[srow * 40 + skc] = pa;
    {
      unsigned short t8[8];
#pragma unroll
      for (int i = 0; i < 4; i++) { t8[i] = f2b(f0[i]); t8[4 + i] = f2b(f1[i]); }
      unsigned short* dst = &Bs[bk * 66 + bd];
#pragma unroll
      for (int w2 = 0; w2 < 4; w2++) *(unsigned*)(dst + w2 * 2) = ((unsigned*)t8)[w2];
    }
    if (k0 + 32 < 1024) {
      pa = *(const uint4*)(attnb + abase + (long)srow * 2048 + (k0 + 32) + skc);
      f0 = *(const floatx4*)(tokf + tbase + (long)(k0 + 32 + bk) * 768 + n0 + bd);
      f1 = *(const floatx4*)(tokf + tbase + (long)(k0 + 32 + bk) * 768 + n0 + bd + 4);
    }
    asm volatile("s_waitcnt lgkmcnt(0)" ::: "memory");
    __builtin_amdgcn_s_barrier();
    __builtin_amdgcn_sched_barrier(0);

    shortx8 a0 = *(const shortx8*)&As[(wm * 32 + 0  + l16) * 40 + quad * 8];
    shortx8 a1 = *(const shortx8*)&As[(wm * 32 + 16 + l16) * 40 + quad * 8];
    shortx8 b0, b1;
#pragma unroll
    for (int j = 0; j < 8; j++) {
      b0[j] = *(const short*)&Bs[(quad * 8 + j) * 66 + wn * 32 + l16];
      b1[j] = *(const short*)&Bs[(quad * 8 + j) * 66 + wn * 32 + 16 + l16];
    }
    acc[0][0] = __builtin_amdgcn_mfma_f32_16x16x32_bf16(a0, b0, acc[0][0], 0, 0, 0);
    acc[0][1] = __builtin_amdgcn_mfma_f32_16x16x32_bf16(a0, b1, acc[0][1], 0, 0, 0);
    acc[1][0] = __builtin_amdgcn_mfma_f32_16x16x32_bf16(a1, b0, acc[1][0], 0, 0, 0);
    acc[1][1] = __builtin_amdgcn_mfma_f32_16x16x32_bf16(a1, b1, acc[1][1], 0, 0, 0);
    __builtin_amdgcn_s_barrier();
  }

#pragma unroll
  for (int im = 0; im < 2; im++)
#pragma unroll
    for (int in_ = 0; in_ < 2; in_++) {
      const int rbase = wm * 32 + im * 16 + quad * 4;
      const int c = n0 + wn * 32 + in_ * 16 + l16;
#pragma unroll
      for (int r = 0; r < 4; r++)
        parts[(long)kc * 786432 + ((long)b * 64 + rbase + r) * 768 + c] =
            acc[im][in_][r];
    }
}

// ---------------- routed LayerNorm -> conc second half + candA second half --
__global__ __launch_bounds__(256) void k_ln_routed(
    const float* __restrict__ routed,
    const float* __restrict__ g_in, const float* __restrict__ be_in,
    unsigned short* __restrict__ conc, unsigned short* __restrict__ candA) {
  __shared__ float scr[4];
  const long r = blockIdx.x;
  const int t = threadIdx.x;
  floatx4 v = *(const floatx4*)(routed + r * 1024 + t * 4);
  float s1 = v[0] + v[1] + v[2] + v[3];
  float s2 = v[0] * v[0] + v[1] * v[1] + v[2] * v[2] + v[3] * v[3];
  s1 = block_sum(s1, scr);
  s2 = block_sum(s2, scr);
  const float mean = s1 * (1.0f / 1024.0f);
  const float var = s2 * (1.0f / 1024.0f) - mean * mean;
  const float rstd = rsqrtf(var + LN_EPS);
  unsigned short t4[4];
#pragma unroll
  for (int i = 0; i < 4; i++) {
    const int d = t * 4 + i;
    t4[i] = f2b((v[i] - mean) * rstd * g_in[d] + be_in[d]);
  }
  *(uint2*)(conc + r * 2048 + 1024 + t * 4) = *(uint2*)t4;
  *(uint2*)(candA + r * 2048 + 1024 + t * 4) = *(uint2*)t4;
}

// ---------------- gates epilogue: sigmoid(p0+p1+bias) -> ubuf / r*psn -------
__global__ __launch_bounds__(256) void k_gate_epi(
    const float* __restrict__ gparts,  // [2][1024][2048]
    const float* __restrict__ bu, const float* __restrict__ br,
    const unsigned short* __restrict__ conc,
    float* __restrict__ ubuf, unsigned short* __restrict__ candA) {
  const int row = blockIdx.x >> 1;
  const int half = blockIdx.x & 1;
  const int t = threadIdx.x;
  const long base = (long)row * 2048 + half * 1024 + t * 4;
  floatx4 p0 = *(const floatx4*)(gparts + base);
  floatx4 p1 = *(const floatx4*)(gparts + 2097152 + base);
  const float* bias = half ? br : bu;
  floatx4 bv = *(const floatx4*)(bias + t * 4);
  if (!half) {
    floatx4 o;
#pragma unroll
    for (int i = 0; i < 4; i++)
      o[i] = 1.0f / (1.0f + expf(-(p0[i] + p1[i] + bv[i])));
    *(floatx4*)(ubuf + (long)row * 1024 + t * 4) = o;
  } else {
    unsigned short t4[4];
#pragma unroll
    for (int i = 0; i < 4; i++) {
      float rr = 1.0f / (1.0f + expf(-(p0[i] + p1[i] + bv[i])));
      t4[i] = f2b(rr * b2f(conc[(long)row * 2048 + t * 4 + i]));
    }
    *(uint2*)(candA + (long)row * 2048 + t * 4) = *(uint2*)t4;
  }
}

// ---------------- final: cand-epilogue + LayerNorm -> f32 output ------------
__global__ __launch_bounds__(256) void k_ln_out(
    const float* __restrict__ cparts,  // [2][1024][1024]
    const float* __restrict__ ubuf, const float* __restrict__ prev,
    const float* __restrict__ bn,
    const float* __restrict__ g, const float* __restrict__ be,
    float* __restrict__ out) {
  __shared__ float scr[4];
  const long r = blockIdx.x;
  const int t = threadIdx.x;
  floatx4 p0 = *(const floatx4*)(cparts + r * 1024 + t * 4);
  floatx4 p1 = *(const floatx4*)(cparts + 1048576 + r * 1024 + t * 4);
  floatx4 uu = *(const floatx4*)(ubuf + r * 1024 + t * 4);
  floatx4 pv = *(const floatx4*)(prev + r * 1024 + t * 4);
  floatx4 bv = *(const floatx4*)(bn + t * 4);
  floatx4 v;
#pragma unroll
  for (int i = 0; i < 4; i++) {
    const float cand = tanhf(p0[i] + p1[i] + bv[i]);
    v[i] = (1.0f - uu[i]) * pv[i] + uu[i] * cand;
  }
  float s1 = v[0] + v[1] + v[2] + v[3];
  float s2 = v[0] * v[0] + v[1] * v[1] + v[2] * v[2] + v[3] * v[3];
  s1 = block_sum(s1, scr);
  s2 = block_sum(s2, scr);
  const float mean = s1 * (1.0f / 1024.0f);
  const float var = s2 * (1.0f / 1024.0f) - mean * mean;
  const float rstd = rsqrtf(var + LN_EPS);
  floatx4 o;
#pragma unroll
  for (int i = 0; i < 4; i++) {
    const int d = t * 4 + i;
    o[i] = (v[i] - mean) * rstd * g[d] + be[d];
  }
  *(floatx4*)(out + r * 1024 + t * 4) = o;
}

// ---------------------------------------------------------------------------
extern "C" void kernel_launch(void* const* d_in, const int* in_sizes, int n_in,
                              void* d_out, int out_size, void* d_ws, size_t ws_size,
                              hipStream_t stream) {
  (void)in_sizes; (void)n_in; (void)out_size; (void)ws_size;
  const float* prev  = (const float*)d_in[0];
  const float* toks  = (const float*)d_in[1];
  const float* Wp    = (const float*)d_in[2];
  const float* bp    = (const float*)d_in[3];
  const float* g_st  = (const float*)d_in[4];
  const float* be_st = (const float*)d_in[5];
  const float* g_in  = (const float*)d_in[6];
  const float* be_in = (const float*)d_in[7];
  const float* g_o   = (const float*)d_in[8];
  const float* be_o  = (const float*)d_in[9];
  const float* Wu    = (const float*)d_in[10];
  const float* bu    = (const float*)d_in[11];
  const float* Wr    = (const float*)d_in[12];
  const float* br    = (const float*)d_in[13];
  const float* Wn    = (const float*)d_in[14];
  const float* bn    = (const float*)d_in[15];
  float* out = (float*)d_out;

  // ---- workspace (~70 MB)
  char* ws = (char*)d_ws;
  unsigned short* Wtp   = (unsigned short*)ws; ws += 1572864;   // 1024x768 bf16
  unsigned short* pwb   = (unsigned short*)ws; ws += 1572864;   // 1024x768 bf16
  unsigned short* attnb = (unsigned short*)ws; ws += 4194304;   // 16x64x2048 bf16
  float*          rowsum= (float*)ws;          ws += 4096;      // 1024 f32
  float*          parts = (float*)ws;          ws += 6291456;   // 2x 1024x768 f32
  float*          routed= (float*)ws;          ws += 4194304;   // 1024x1024 f32
  unsigned short* conc  = (unsigned short*)ws; ws += 4194304;   // 1024x2048 bf16
  unsigned short* candA = (unsigned short*)ws; ws += 4194304;   // 1024x2048 bf16
  float*          ubuf  = (float*)ws;          ws += 4194304;   // 1024x1024 f32
  unsigned short* Wtur  = (unsigned short*)ws; ws += 8388608;   // 2048x2048 bf16
  unsigned short* Wtn   = (unsigned short*)ws; ws += 4194304;   // 1024x2048 bf16
  float*          gparts= (float*)ws;          ws += 16777216;  // 2x 1024x2048 f32
  float*          cparts= (float*)ws;          ws += 8388608;   // 2x 1024x1024 f32

  const dim3 blk(256);

  // 1. merged: pw GEMM (f32-direct) + 4 transposes + rowsum zero
  k_prep_pw<<<dim3(7104), blk, 0, stream>>>(prev, Wp, Wu, Wr, Wn,
                                            Wtur, Wtn, Wtp, pwb, rowsum);
  // 2. attnb = exp(pw @ tokens^T / 32) + fused rowsum atomics, 512 blocks
  k_scores<<<dim3(1, 32, 16), blk, 0, stream>>>(
      pwb, 49152L, 768, toks, 768, 0.03125f,
      attnb, 2048, 131072L, rowsum);
  // 3. rw partials = w @ tokens(f32), K-split x2, 384 blocks
  k_routed_mfma<<<dim3(2, 12, 16), blk, 0, stream>>>(attnb, toks, parts);
  // 4. merged: proj2 (256 blocks) + prev-LN (1024 blocks)
  k_proj2_ln<<<dim3(1280), blk, 0, stream>>>(
      parts, 768, Wtp, 768, 768, bp, rowsum, routed, 1024,
      prev, g_st, be_st, conc);
  // 5. routed LN -> conc/candA second halves
  k_ln_routed<<<dim3(1024), blk, 0, stream>>>(routed, g_in, be_in, conc, candA);
  // 6. u|r gates GEMM, K-split x2 (f32 partials), 1024 blocks
  k_gemm64<<<dim3(16, 32, 2), blk, 0, stream>>>(
      conc, 2048, Wtur, 2048, 1024, 2097152L, gparts, 2048);
  // 7. gates epilogue: sigmoid + r*ps_n, 2048 blocks
  k_gate_epi<<<dim3(2048), blk, 0, stream>>>(gparts, bu, br, conc, ubuf, candA);
  // 8. cand GEMM, K-split x2 (f32 partials), 512 blocks
  k_gemm64<<<dim3(16, 16, 2), blk, 0, stream>>>(
      candA, 2048, Wtn, 2048, 1024, 1048576L, cparts, 1024);
  // 9. fused cand-epilogue + final LN -> output
  k_ln_out<<<dim3(1024), blk, 0, stream>>>(cparts, ubuf, prev, bn, g_o, be_o, out);
}